// Round 8
// baseline (636.014 us; speedup 1.0000x reference)
//
#include <hip/hip_runtime.h>
#include <math.h>

// Problem dims
#define L_DIM 2048
#define B_DIM 16
#define D_DIM 512
#define H_DIM 1024
#define Z_DIM 128
#define NC    16
#define BASE_N 2176            // Z + H + 2D
#define ROWS  (L_DIM*B_DIM)    // 32768
#define NSEG  32
#define SLEN  64
#define CHAINS 8192            // B*D

typedef unsigned short bf16_t;
typedef __attribute__((ext_vector_type(8))) short short8;
typedef __attribute__((ext_vector_type(4))) float f32x4;

__device__ __forceinline__ float sigmoidf_(float x){ return 1.f/(1.f+__expf(-x)); }
__device__ __forceinline__ float siluf_(float x){ return x/(1.f+__expf(-x)); }
__device__ __forceinline__ float fbits(unsigned int b){ union{unsigned int i; float f;} c; c.i=b; return c.f; }
__device__ __forceinline__ unsigned short f2bf(float f){
  union{float f; unsigned int i;} c; c.f=f;
  unsigned int r = c.i + 0x7FFFu + ((c.i>>16)&1u);   // RNE
  return (unsigned short)(r>>16);
}
__device__ __forceinline__ float bf2f(unsigned short u){ return fbits(((unsigned int)u)<<16); }

__device__ __forceinline__ void load8(const float* __restrict__ p, float* d){
  float4 a = *(const float4*)p; float4 b = *(const float4*)(p+4);
  d[0]=a.x; d[1]=a.y; d[2]=a.z; d[3]=a.w; d[4]=b.x; d[5]=b.y; d[6]=b.z; d[7]=b.w;
}
__device__ __forceinline__ void load8(const bf16_t* __restrict__ p, float* d){
  uint4 u = *(const uint4*)p;
  d[0]=fbits(u.x<<16); d[1]=fbits(u.x&0xFFFF0000u);
  d[2]=fbits(u.y<<16); d[3]=fbits(u.y&0xFFFF0000u);
  d[4]=fbits(u.z<<16); d[5]=fbits(u.z&0xFFFF0000u);
  d[6]=fbits(u.w<<16); d[7]=fbits(u.w&0xFFFF0000u);
}
__device__ __forceinline__ void store8bf(bf16_t* p, const float* v){
  uint4 s;
  s.x = (unsigned int)f2bf(v[0]) | ((unsigned int)f2bf(v[1])<<16);
  s.y = (unsigned int)f2bf(v[2]) | ((unsigned int)f2bf(v[3])<<16);
  s.z = (unsigned int)f2bf(v[4]) | ((unsigned int)f2bf(v[5])<<16);
  s.w = (unsigned int)f2bf(v[6]) | ((unsigned int)f2bf(v[7])<<16);
  *(uint4*)p = s;
}

// async global(16B/lane) -> LDS, wave-uniform LDS base + lane*16
__device__ __forceinline__ void glds16(const void* g, void* l) {
  __builtin_amdgcn_global_load_lds(
      (const __attribute__((address_space(1))) unsigned int*)g,
      (__attribute__((address_space(3))) unsigned int*)l, 16, 0, 0);
}

// ---------------------------------------------------------------------------
// All three weight transposes in one launch. W (K x N fp32) -> Wt (N x K bf16)
// ---------------------------------------------------------------------------
__global__ __launch_bounds__(256) void transpose_all_kernel(
    const float* __restrict__ Wv, const float* __restrict__ Wmx,
    const float* __restrict__ Wh, bf16_t* __restrict__ Wvt,
    bf16_t* __restrict__ Wmxt, bf16_t* __restrict__ Wht)
{
  __shared__ float t[32][33];
  int blk = blockIdx.x;
  const float* W; bf16_t* Wt; int K, N, bx, by;
  if (blk < 512)       { W=Wv;  Wt=Wvt;  K=512;  N=1024; bx=blk&31;  by=blk>>5; }
  else if (blk < 1600) { blk-=512;  W=Wmx; Wt=Wmxt; K=512;  N=2176; bx=blk%68; by=blk/68; }
  else                 { blk-=1600; W=Wh;  Wt=Wht;  K=1024; N=512;  bx=blk&15; by=blk>>4; }
  int lx = threadIdx.x & 31, ly = threadIdx.x >> 5;
  #pragma unroll
  for (int i = 0; i < 32; i += 8)
    t[ly+i][lx] = W[(size_t)(by*32+ly+i)*N + bx*32 + lx];
  __syncthreads();
  #pragma unroll
  for (int i = 0; i < 32; i += 8)
    Wt[(size_t)(bx*32+ly+i)*K + by*32 + lx] = f2bf(t[lx][ly+i]);
}

// ---------------------------------------------------------------------------
// EMA segmented scan, SLEN=64, NSEG=32. Chains c = b*512+d (8192).
// Backward scan uses bf16-rounded x kept in registers (no xb re-read).
// ---------------------------------------------------------------------------
__global__ __launch_bounds__(256) void ema_carry_kernel(
    const float* __restrict__ x, const float* __restrict__ delta,
    const float* __restrict__ alpha, bf16_t* __restrict__ xb,
    float* __restrict__ carry)
{
  int idx = blockIdx.x*256 + threadIdx.x;      // 0..262143
  int d = idx & 511, c = idx & 8191, s = idx >> 13;   // s in 0..31
  float qf0 = 1.f - sigmoidf_(delta[d*2+0])*sigmoidf_(alpha[d*2+0]);
  float qf1 = 1.f - sigmoidf_(delta[d*2+1])*sigmoidf_(alpha[d*2+1]);
  int dd = d + 512;
  float qb0 = 1.f - sigmoidf_(delta[dd*2+0])*sigmoidf_(alpha[dd*2+0]);
  float qb1 = 1.f - sigmoidf_(delta[dd*2+1])*sigmoidf_(alpha[dd*2+1]);
  size_t off = (size_t)s*SLEN*CHAINS + c;
  float xr[SLEN];
  float h0=0.f, h1=0.f;
  #pragma unroll
  for (int t = 0; t < SLEN; ++t) {
    size_t a = off + (size_t)t*CHAINS;
    float xv = x[a];
    unsigned short xv16 = f2bf(xv);
    xb[a] = xv16;
    xr[t] = bf2f(xv16);
    h0 = fmaf(qf0, h0, xv); h1 = fmaf(qf1, h1, xv);
  }
  float g0=0.f, g1=0.f;
  #pragma unroll
  for (int t = SLEN-1; t >= 0; --t) {
    float xv = xr[t];
    g0 = fmaf(qb0, g0, xv); g1 = fmaf(qb1, g1, xv);
  }
  carry[(size_t)s*CHAINS + c]              = h0;
  carry[(size_t)s*CHAINS + c + 262144]     = h1;
  carry[(size_t)s*CHAINS + c + 524288]     = g0;
  carry[(size_t)s*CHAINS + c + 786432]     = g1;
}

__global__ __launch_bounds__(256) void ema_combine_kernel(
    const float* __restrict__ delta, const float* __restrict__ alpha,
    float* __restrict__ carry)
{
  int c = blockIdx.x*256 + threadIdx.x;   // 0..8191
  int d = c & 511;
  float qf0 = 1.f - sigmoidf_(delta[d*2+0])*sigmoidf_(alpha[d*2+0]);
  float qf1 = 1.f - sigmoidf_(delta[d*2+1])*sigmoidf_(alpha[d*2+1]);
  int dd = d + 512;
  float qb0 = 1.f - sigmoidf_(delta[dd*2+0])*sigmoidf_(alpha[dd*2+0]);
  float qb1 = 1.f - sigmoidf_(delta[dd*2+1])*sigmoidf_(alpha[dd*2+1]);
  float df0=qf0, df1=qf1, db0=qb0, db1=qb1;
  #pragma unroll
  for (int i = 0; i < 6; ++i) { df0*=df0; df1*=df1; db0*=db0; db1*=db1; }  // q^64
  float h0=0.f, h1=0.f;
  for (int s = 0; s < NSEG; ++s) {
    size_t a = (size_t)s*CHAINS + c;
    float t0 = carry[a], t1 = carry[a+262144];
    carry[a] = h0; carry[a+262144] = h1;
    h0 = fmaf(df0, h0, t0); h1 = fmaf(df1, h1, t1);
  }
  float g0=0.f, g1=0.f;
  for (int s = NSEG-1; s >= 0; --s) {
    size_t a = (size_t)s*CHAINS + c;
    float t0 = carry[a+524288], t1 = carry[a+786432];
    carry[a+524288] = g0; carry[a+786432] = g1;
    g0 = fmaf(db0, g0, t0); g1 = fmaf(db1, g1, t1);
  }
}

__global__ __launch_bounds__(256) void ema_apply_kernel(
    const bf16_t* __restrict__ xb, const float* __restrict__ delta,
    const float* __restrict__ alpha, const float* __restrict__ beta,
    const float* __restrict__ gamma, const float* __restrict__ omega,
    const float* __restrict__ carry, bf16_t* __restrict__ mx)
{
  int idx = blockIdx.x*256 + threadIdx.x;
  int d = idx & 511, c = idx & 8191, s = idx >> 13;
  const float rs = 0.70710678118654752f;
  float pf0 = sigmoidf_(delta[d*2+0]), pf1 = sigmoidf_(delta[d*2+1]);
  float qf0 = 1.f - pf0*sigmoidf_(alpha[d*2+0]);
  float qf1 = 1.f - pf1*sigmoidf_(alpha[d*2+1]);
  float cf0 = pf0*beta[d*2+0]*gamma[d*2+0]*rs;
  float cf1 = pf1*beta[d*2+1]*gamma[d*2+1]*rs;
  int dd = d + 512;
  float pb0 = sigmoidf_(delta[dd*2+0]), pb1 = sigmoidf_(delta[dd*2+1]);
  float qb0 = 1.f - pb0*sigmoidf_(alpha[dd*2+0]);
  float qb1 = 1.f - pb1*sigmoidf_(alpha[dd*2+1]);
  float cb0 = pb0*beta[dd*2+0]*gamma[dd*2+0]*rs;
  float cb1 = pb1*beta[dd*2+1]*gamma[dd*2+1]*rs;
  float om = omega[d];
  size_t off = (size_t)s*SLEN*CHAINS + c;
  float h0 = carry[(size_t)s*CHAINS + c];
  float h1 = carry[(size_t)s*CHAINS + c + 262144];
  float yv[SLEN];
  #pragma unroll
  for (int t = 0; t < SLEN; ++t) {
    float xv = bf2f(xb[off + (size_t)t*CHAINS]);
    h0 = fmaf(qf0, h0, xv); h1 = fmaf(qf1, h1, xv);
    yv[t] = fmaf(cf0, h0, cf1*h1);
  }
  float g0 = carry[(size_t)s*CHAINS + c + 524288];
  float g1 = carry[(size_t)s*CHAINS + c + 786432];
  #pragma unroll
  for (int t = SLEN-1; t >= 0; --t) {
    size_t a = off + (size_t)t*CHAINS;
    float xv = bf2f(xb[a]);
    g0 = fmaf(qb0, g0, xv); g1 = fmaf(qb1, g1, xv);
    float sv = yv[t] + fmaf(cb0, g0, cb1*g1) + xv*om;
    mx[a] = f2bf(siluf_(sv));
  }
}

// ===========================================================================
// Shared MFMA K-loop core (round-7 verified): BM=128 x BN=64 tile, acc[4][2],
// single-buffer BK=64, XOR-swizzled LDS. 24576 B -> 6 blocks/CU.
// ===========================================================================
#define GEMM_SMEM                                                            \
  __shared__ __align__(16) char smem[24576];                                 \
  bf16_t* As = (bf16_t*)smem;            /* 128x64 */                        \
  bf16_t* Bs = (bf16_t*)(smem + 16384);  /* 64x64  */                        \
  bf16_t* Cs = (bf16_t*)smem;            /* 128x72, reused after K-loop */

#define GEMM_PROLOG(Aptr, Bptr, Kdim)                                        \
  int tid = threadIdx.x;                                                     \
  int wave = tid >> 6, lane = tid & 63;                                      \
  int lrow = lane >> 3, lchunk = ((lane & 7) - lrow) & 7;                    \
  const bf16_t* Ag = (Aptr) + (size_t)(wave*32 + lrow)*(Kdim) + lchunk*8;    \
  const bf16_t* Bg = (Bptr) + (size_t)(wave*16 + lrow)*(Kdim) + lchunk*8;    \
  int wm = wave >> 1, wn = wave & 1;                                         \
  int fr = lane & 15, fq = lane >> 4;                                        \
  f32x4 acc[4][2];                                                           \
  _Pragma("unroll") for (int i = 0; i < 4; ++i)                              \
    _Pragma("unroll") for (int j = 0; j < 2; ++j)                            \
      acc[i][j] = (f32x4){0.f,0.f,0.f,0.f};

#define GEMM_KLOOP(Kdim)                                                     \
  for (int k0 = 0; k0 < (Kdim); k0 += 64) {                                  \
    __syncthreads();                                                         \
    _Pragma("unroll") for (int j = 0; j < 4; ++j)                            \
      glds16(Ag + (size_t)j*8*(Kdim) + k0, As + (wave*32 + j*8)*64);         \
    _Pragma("unroll") for (int j = 0; j < 2; ++j)                            \
      glds16(Bg + (size_t)j*8*(Kdim) + k0, Bs + (wave*16 + j*8)*64);         \
    __syncthreads();                                                         \
    _Pragma("unroll") for (int kk = 0; kk < 2; ++kk) {                       \
      short8 af[4], bfr[2];                                                  \
      _Pragma("unroll") for (int mi = 0; mi < 4; ++mi) {                     \
        int R = wm*64 + mi*16 + fr;                                          \
        af[mi] = *(const short8*)&As[R*64 + (((kk<<2)+fq+R)&7)*8];           \
      }                                                                      \
      _Pragma("unroll") for (int ni = 0; ni < 2; ++ni) {                     \
        int R = wn*32 + ni*16 + fr;                                          \
        bfr[ni] = *(const short8*)&Bs[R*64 + (((kk<<2)+fq+R)&7)*8];          \
      }                                                                      \
      _Pragma("unroll") for (int mi = 0; mi < 4; ++mi)                       \
        _Pragma("unroll") for (int ni = 0; ni < 2; ++ni)                     \
          acc[mi][ni] = __builtin_amdgcn_mfma_f32_16x16x32_bf16(             \
              af[mi], bfr[ni], acc[mi][ni], 0, 0, 0);                        \
    }                                                                        \
  }

// ---------------------------------------------------------------------------
// Generic MFMA bf16 GEMM: C(bf16, MxN) = act(A @ Bt^T + bias [+ Add])
// 128x64 tile, XCD-swizzled 1-D grid. Epilogue repacks via LDS, dwordx4.
// ---------------------------------------------------------------------------
__global__ __launch_bounds__(256, 6) void mfma_gemm_kernel(
    const bf16_t* __restrict__ A, const bf16_t* __restrict__ Bt,
    const float* __restrict__ bias, const bf16_t* __restrict__ Add, int addLd,
    bf16_t* __restrict__ C, int N, int K, int nT, int act)
{
  GEMM_SMEM
  int flat = blockIdx.x;
  int xcd = flat & 7, g = flat >> 3;
  int mT8 = (int)(gridDim.x / (unsigned)nT) >> 3;
  int mt = xcd*mT8 + g / nT;
  int nt = g % nT;
  int m0 = mt*128, n0 = nt*64;
  GEMM_PROLOG(A + (size_t)m0*K, Bt + (size_t)n0*K, K)
  GEMM_KLOOP(K)
  __syncthreads();
  #pragma unroll
  for (int ni = 0; ni < 2; ++ni) {
    int cl = wn*32 + ni*16 + fr;
    int gn = n0 + cl;
    float bv = bias[gn];
    #pragma unroll
    for (int mi = 0; mi < 4; ++mi) {
      #pragma unroll
      for (int r = 0; r < 4; ++r) {
        int ml = wm*64 + mi*16 + fq*4 + r;
        float val = acc[mi][ni][r] + bv;
        if (Add) val += bf2f(Add[(size_t)(m0+ml)*addLd + gn]);
        if (act == 1) val = siluf_(val);
        Cs[ml*72 + cl] = f2bf(val);
      }
    }
  }
  __syncthreads();
  int row = tid >> 1, c0 = (tid & 1)*32;
  #pragma unroll
  for (int q = 0; q < 4; ++q)
    *(uint4*)(C + (size_t)(m0+row)*N + n0 + c0 + q*8) =
        *(const uint4*)&Cs[row*72 + c0 + q*8];
}

// ---------------------------------------------------------------------------
// Wv GEMM variant: vt[b][nchunk][h][k] = silu(x @ Wv + bv), transposed per
// 128-chunk so PV can consume it as an N x K "Bt". N = 1024, K = 512.
// Tile is 128x64: repack covers 64 h-columns; threads 0..127 do the writes.
// ---------------------------------------------------------------------------
__global__ __launch_bounds__(256, 6) void mfma_gemm_v_kernel(
    const bf16_t* __restrict__ A, const bf16_t* __restrict__ Bt,
    const float* __restrict__ bias, bf16_t* __restrict__ vt, int nT, int K)
{
  GEMM_SMEM
  int flat = blockIdx.x;
  int xcd = flat & 7, g = flat >> 3;
  int mT8 = (int)(gridDim.x / (unsigned)nT) >> 3;
  int mt = xcd*mT8 + g / nT;
  int nt = g % nT;
  int m0 = mt*128, n0 = nt*64;
  GEMM_PROLOG(A + (size_t)m0*K, Bt + (size_t)n0*K, K)
  GEMM_KLOOP(K)
  __syncthreads();
  #pragma unroll
  for (int ni = 0; ni < 2; ++ni) {
    int cl = wn*32 + ni*16 + fr;
    float bv = bias[n0 + cl];
    #pragma unroll
    for (int mi = 0; mi < 4; ++mi) {
      #pragma unroll
      for (int r = 0; r < 4; ++r) {
        int ml = wm*64 + mi*16 + fq*4 + r;
        Cs[ml*72 + cl] = f2bf(siluf_(acc[mi][ni][r] + bv));
      }
    }
  }
  __syncthreads();
  // Tile rows gm = m0 + (kk*16 + b): vt[(b*16+nchunk)*1024 + h][k],
  // nchunk = mt>>4, k = (mt&15)*8 + kk. 64 h-cols -> threads 0..127.
  if (tid < 128) {
    int b = tid >> 3, h0l = (tid & 7)*8;
    int nchunk = mt >> 4, kbase = (mt & 15)*8;
    #pragma unroll
    for (int j = 0; j < 8; ++j) {
      int hl = h0l + j;
      uint4 s;
      s.x = (unsigned int)Cs[(0*16 + b)*72 + hl] |
            ((unsigned int)Cs[(1*16 + b)*72 + hl] << 16);
      s.y = (unsigned int)Cs[(2*16 + b)*72 + hl] |
            ((unsigned int)Cs[(3*16 + b)*72 + hl] << 16);
      s.z = (unsigned int)Cs[(4*16 + b)*72 + hl] |
            ((unsigned int)Cs[(5*16 + b)*72 + hl] << 16);
      s.w = (unsigned int)Cs[(6*16 + b)*72 + hl] |
            ((unsigned int)Cs[(7*16 + b)*72 + hl] << 16);
      *(uint4*)&vt[((size_t)(b*NC + nchunk)*H_DIM + n0 + hl)*128 + kbase] = s;
    }
  }
}

// ---------------------------------------------------------------------------
// FUSED attention: scores (QK^T + softmax -> attn_out fp32) then PV
// (hr = (P@V)*silu(r)) without the p_bf global round-trip.
// One block per (b,n), 256 blocks. P lives in LDS (overlay of qs).
// LDS: ps 128x136 (34816) | Vs 64x136 (17408) | Cs 128x72 (18432) = 70656 B.
// V tiles (16 KB contiguous in vt) are reg-staged with 1-tile prefetch.
// ---------------------------------------------------------------------------
__global__ __launch_bounds__(256) void attn_fused_kernel(
    const bf16_t* __restrict__ base, const float* __restrict__ qkg,
    const float* __restrict__ qkb, const float* __restrict__ rpb,
    float* __restrict__ attn_out, const bf16_t* __restrict__ vt,
    bf16_t* __restrict__ hr)
{
  __shared__ __align__(16) char smem[70656];
  bf16_t* qs = (bf16_t*)smem;                 // 128x136, becomes ps
  bf16_t* ks = (bf16_t*)(smem + 34816);       // 128x136
  bf16_t* ps = qs;                            // P bf16 128x136 (phase 2)
  bf16_t* Vs = ks;                            // V tile 64x136 (phase 2)
  bf16_t* Cs = (bf16_t*)(smem + 52224);       // 128x72 epilogue
  int blk = blockIdx.x;            // b*16 + n
  int b = blk >> 4, n = blk & 15;
  int tid = threadIdx.x;
  {
    int r = tid >> 1, z0 = (tid & 1)*64;
    size_t rowoff = ((size_t)((n*128 + r)*B_DIM + b))*BASE_N + 512 + z0;
    #pragma unroll
    for (int cchunk = 0; cchunk < 8; ++cchunk) {
      float t8[8], qv[8], kv[8];
      load8(base + rowoff + cchunk*8, t8);
      #pragma unroll
      for (int j = 0; j < 8; ++j) {
        int z = z0 + cchunk*8 + j;
        float zs = siluf_(t8[j]);
        qv[j] = fmaf(zs, qkg[z],     qkb[z]);
        kv[j] = fmaf(zs, qkg[128+z], qkb[128+z]);
      }
      store8bf(&qs[r*136 + z0 + cchunk*8], qv);
      store8bf(&ks[r*136 + z0 + cchunk*8], kv);
    }
  }
  __syncthreads();
  int wave = tid >> 6, lane = tid & 63;
  int fr = lane & 15, fq = lane >> 4;
  f32x4 acc[2][8];
  #pragma unroll
  for (int i = 0; i < 2; ++i)
    #pragma unroll
    for (int j = 0; j < 8; ++j)
      acc[i][j] = (f32x4){0.f,0.f,0.f,0.f};
  #pragma unroll
  for (int kk = 0; kk < 4; ++kk) {
    short8 af[2], bfr[8];
    #pragma unroll
    for (int mi = 0; mi < 2; ++mi)
      af[mi] = *(const short8*)&qs[(wave*32 + mi*16 + fr)*136 + kk*32 + fq*8];
    #pragma unroll
    for (int ni = 0; ni < 8; ++ni)
      bfr[ni] = *(const short8*)&ks[(ni*16 + fr)*136 + kk*32 + fq*8];
    #pragma unroll
    for (int mi = 0; mi < 2; ++mi)
      #pragma unroll
      for (int ni = 0; ni < 8; ++ni)
        acc[mi][ni] = __builtin_amdgcn_mfma_f32_16x16x32_bf16(
            af[mi], bfr[ni], acc[mi][ni], 0, 0, 0);
  }
  const float scale = 0.08838834764831845f;  // 1/sqrt(128)
  float mrow[2][4], srow[2][4];
  #pragma unroll
  for (int mi = 0; mi < 2; ++mi)
    #pragma unroll
    for (int r = 0; r < 4; ++r) mrow[mi][r] = -1e30f;
  #pragma unroll
  for (int mi = 0; mi < 2; ++mi)
    #pragma unroll
    for (int ni = 0; ni < 8; ++ni)
      #pragma unroll
      for (int r = 0; r < 4; ++r) {
        int i = wave*32 + mi*16 + fq*4 + r;
        int j = ni*16 + fr;
        float v = fmaf(acc[mi][ni][r], scale, rpb[1023 + j - i]);
        acc[mi][ni][r] = v;
        mrow[mi][r] = fmaxf(mrow[mi][r], v);
      }
  #pragma unroll
  for (int mi = 0; mi < 2; ++mi)
    #pragma unroll
    for (int r = 0; r < 4; ++r) {
      float m = mrow[mi][r];
      m = fmaxf(m, __shfl_xor(m, 1));
      m = fmaxf(m, __shfl_xor(m, 2));
      m = fmaxf(m, __shfl_xor(m, 4));
      m = fmaxf(m, __shfl_xor(m, 8));
      mrow[mi][r] = m;
      srow[mi][r] = 0.f;
    }
  #pragma unroll
  for (int mi = 0; mi < 2; ++mi)
    #pragma unroll
    for (int ni = 0; ni < 8; ++ni)
      #pragma unroll
      for (int r = 0; r < 4; ++r) {
        float e = __expf(acc[mi][ni][r] - mrow[mi][r]);
        acc[mi][ni][r] = e;
        srow[mi][r] += e;
      }
  #pragma unroll
  for (int mi = 0; mi < 2; ++mi)
    #pragma unroll
    for (int r = 0; r < 4; ++r) {
      float s = srow[mi][r];
      s += __shfl_xor(s, 1);
      s += __shfl_xor(s, 2);
      s += __shfl_xor(s, 4);
      s += __shfl_xor(s, 8);
      srow[mi][r] = 1.f/s;
    }
  // all qs/ks reads are done (kk loop ended) -> safe to overlay ps on qs
  __syncthreads();
  #pragma unroll
  for (int mi = 0; mi < 2; ++mi)
    #pragma unroll
    for (int r = 0; r < 4; ++r) {
      int i = wave*32 + mi*16 + fq*4 + r;
      size_t o = ((size_t)blk*128 + i)*128;
      #pragma unroll
      for (int ni = 0; ni < 8; ++ni) {
        float val = acc[mi][ni][r]*srow[mi][r];
        attn_out[o + ni*16 + fr] = val;
        ps[i*136 + ni*16 + fr] = f2bf(val);
      }
    }
  // ---- Phase 2: hr = (P @ V) * silu(r), 16 h-tiles of 64 ----
  int wm = wave >> 1, wn = wave & 1;
  const bf16_t* vbase = vt + (size_t)blk*H_DIM*128;
  uint4 vbuf[4];
  {
    const uint4* src = (const uint4*)vbase;
    #pragma unroll
    for (int it = 0; it < 4; ++it) vbuf[it] = src[it*256 + tid];
  }
  for (int ht = 0; ht < 16; ++ht) {
    // write staged V tile into Vs[64][136]
    #pragma unroll
    for (int it = 0; it < 4; ++it) {
      int e = (it*256 + tid)*8;          // element 0..8191
      int row = e >> 7, col = e & 127;
      *(uint4*)&Vs[row*136 + col] = vbuf[it];
    }
    __syncthreads();   // Vs ready; ps fully written (ht=0); prev Cs reads done
    if (ht < 15) {
      const uint4* src = (const uint4*)(vbase + (size_t)(ht+1)*64*128);
      #pragma unroll
      for (int it = 0; it < 4; ++it) vbuf[it] = src[it*256 + tid];
    }
    f32x4 acc2[4][2];
    #pragma unroll
    for (int i = 0; i < 4; ++i)
      #pragma unroll
      for (int j = 0; j < 2; ++j)
        acc2[i][j] = (f32x4){0.f,0.f,0.f,0.f};
    #pragma unroll
    for (int kk = 0; kk < 4; ++kk) {
      short8 af[4], bfr[2];
      #pragma unroll
      for (int mi = 0; mi < 4; ++mi)
        af[mi] = *(const short8*)&ps[(wm*64 + mi*16 + fr)*136 + kk*32 + fq*8];
      #pragma unroll
      for (int ni = 0; ni < 2; ++ni)
        bfr[ni] = *(const short8*)&Vs[(wn*32 + ni*16 + fr)*136 + kk*32 + fq*8];
      #pragma unroll
      for (int mi = 0; mi < 4; ++mi)
        #pragma unroll
        for (int ni = 0; ni < 2; ++ni)
          acc2[mi][ni] = __builtin_amdgcn_mfma_f32_16x16x32_bf16(
              af[mi], bfr[ni], acc2[mi][ni], 0, 0, 0);
    }
    #pragma unroll
    for (int ni = 0; ni < 2; ++ni) {
      int cl = wn*32 + ni*16 + fr;
      int hg = ht*64 + cl;
      #pragma unroll
      for (int mi = 0; mi < 4; ++mi) {
        #pragma unroll
        for (int r = 0; r < 4; ++r) {
          int ml = wm*64 + mi*16 + fq*4 + r;
          size_t rowg = (size_t)((n*128 + ml)*B_DIM + b);
          float rg = bf2f(base[rowg*BASE_N + 640 + hg]);
          Cs[ml*72 + cl] = f2bf(acc2[mi][ni][r]*siluf_(rg));
        }
      }
    }
    __syncthreads();   // Cs ready; all Vs reads (MFMA) complete
    {
      int row = tid >> 1, c0 = (tid & 1)*32;
      size_t rowg = (size_t)((n*128 + row)*B_DIM + b);
      #pragma unroll
      for (int q = 0; q < 4; ++q)
        *(uint4*)(hr + rowg*H_DIM + ht*64 + c0 + q*8) =
            *(const uint4*)&Cs[row*72 + c0 + q*8];
    }
  }
}

// ---------------------------------------------------------------------------
// out = residual + u*(h2 - residual), then RMSNorm * norm_scalar.
// 256 threads = 4 rows per block (one wave per row).
// ---------------------------------------------------------------------------
__global__ __launch_bounds__(256) void final_kernel(
    const float* __restrict__ x, const bf16_t* __restrict__ h2,
    const bf16_t* __restrict__ base, const float* __restrict__ ns,
    float* __restrict__ out)
{
  int row = blockIdx.x*4 + (threadIdx.x >> 6);
  int t = threadIdx.x & 63;
  size_t ro = (size_t)row*D_DIM + t*8;
  float xv[8]; load8(x + ro, xv);
  float hv[8]; load8(h2 + ro, hv);
  float uv[8]; load8(base + (size_t)row*BASE_N + t*8, uv);
  float o[8];
  float ss = 0.f;
  #pragma unroll
  for (int i = 0; i < 8; ++i) {
    float u = sigmoidf_(uv[i]);
    o[i] = xv[i] + u*(hv[i] - xv[i]);
    ss += o[i]*o[i];
  }
  #pragma unroll
  for (int m = 1; m < 64; m <<= 1) ss += __shfl_xor(ss, m);
  float inv = rsqrtf(ss*(1.f/(float)D_DIM) + 1e-6f) * ns[0];
  float4 r0, r1;
  r0.x = o[0]*inv; r0.y = o[1]*inv; r0.z = o[2]*inv; r0.w = o[3]*inv;
  r1.x = o[4]*inv; r1.y = o[5]*inv; r1.z = o[6]*inv; r1.w = o[7]*inv;
  *(float4*)(out + ro) = r0;
  *(float4*)(out + ro + 4) = r1;
}

// ---------------------------------------------------------------------------
extern "C" void kernel_launch(void* const* d_in, const int* in_sizes, int n_in,
                              void* d_out, int out_size, void* d_ws, size_t ws_size,
                              hipStream_t stream)
{
  const float* x     = (const float*)d_in[0];
  const float* delta = (const float*)d_in[1];
  const float* alpha = (const float*)d_in[2];
  const float* beta  = (const float*)d_in[3];
  const float* gamma = (const float*)d_in[4];
  const float* omega = (const float*)d_in[5];
  const float* Wv    = (const float*)d_in[6];
  const float* bv    = (const float*)d_in[7];
  const float* Wmx   = (const float*)d_in[8];
  const float* bmx   = (const float*)d_in[9];
  const float* Wh    = (const float*)d_in[10];
  const float* bh    = (const float*)d_in[11];
  const float* qkg   = (const float*)d_in[12];
  const float* qkb   = (const float*)d_in[13];
  const float* rpb   = (const float*)d_in[14];
  const float* ns    = (const float*)d_in[15];

  float* out  = (float*)d_out;
  float* attn = out + (size_t)ROWS*D_DIM;

  char* outb = (char*)d_out;
  bf16_t* x_bf  = (bf16_t*)outb;            // dead after Wv GEMM
  bf16_t* Wv_t  = (bf16_t*)(outb + 33554432ull);
  bf16_t* Wmx_t = (bf16_t*)(outb + 34603008ull);
  bf16_t* Wh_t  = (bf16_t*)(outb + 36831232ull);

  const size_t WS_NEED = 310378496ull;
  if (ws_size < WS_NEED) return;
  char* wsb = (char*)d_ws;
  bf16_t* mx_bf   = (bf16_t*)(wsb);
  bf16_t* vt      = (bf16_t*)(wsb + 33554432ull);
  bf16_t* base_bf = (bf16_t*)(wsb + 100663296ull);
  bf16_t* hr_bf   = (bf16_t*)(wsb + 243269632ull);
  float*  carry   = (float*)(wsb + 100663296ull);
  bf16_t* h2_bf   = mx_bf;

  // weight transposes (one launch)
  transpose_all_kernel<<<2112, 256, 0, stream>>>(Wv, Wmx, Wh, Wv_t, Wmx_t, Wh_t);
  // EMA segmented scan (also produces x_bf)
  ema_carry_kernel<<<1024, 256, 0, stream>>>(x, delta, alpha, x_bf, carry);
  ema_combine_kernel<<<32, 256, 0, stream>>>(delta, alpha, carry);
  ema_apply_kernel<<<1024, 256, 0, stream>>>(x_bf, delta, alpha, beta, gamma,
                                             omega, carry, mx_bf);
  // vt = silu(x @ Wv + bv), transposed per 128-chunk (N=1024 -> 16 tiles of 64)
  mfma_gemm_v_kernel<<<4096, 256, 0, stream>>>(x_bf, Wv_t, bv, vt, 16, D_DIM);
  // base = mx @ Wmx + bmx (N=2176 -> 34 tiles of 64)
  mfma_gemm_kernel<<<8704, 256, 0, stream>>>(
      mx_bf, Wmx_t, bmx, nullptr, 0, base_bf, BASE_N, D_DIM, 34, 0);
  // fused attn: probs (fp32 -> d_out) + hr = (P @ V) * silu(r)
  attn_fused_kernel<<<B_DIM*NC, 256, 0, stream>>>(
      base_bf, qkg, qkb, rpb, attn, vt, hr_bf);
  // h2 = silu(hx + hr @ Wh + bh) (N=512 -> 8 tiles of 64)
  mfma_gemm_kernel<<<2048, 256, 0, stream>>>(
      hr_bf, Wh_t, bh, base_bf + 1664, BASE_N, h2_bf, D_DIM, H_DIM, 8, 1);
  // gated residual + RMSNorm
  final_kernel<<<ROWS/4, 256, 0, stream>>>(x, h2_bf, base_bf, ns, out);
}

// Round 9
// 584.427 us; speedup vs baseline: 1.0883x; 1.0883x over previous
//
#include <hip/hip_runtime.h>
#include <math.h>

// Problem dims
#define L_DIM 2048
#define B_DIM 16
#define D_DIM 512
#define H_DIM 1024
#define Z_DIM 128
#define NC    16
#define BASE_N 2176            // Z + H + 2D
#define ROWS  (L_DIM*B_DIM)    // 32768
#define NSEG  32
#define SLEN  64
#define CHAINS 8192            // B*D

typedef unsigned short bf16_t;
typedef __attribute__((ext_vector_type(8))) short short8;
typedef __attribute__((ext_vector_type(4))) float f32x4;

__device__ __forceinline__ float sigmoidf_(float x){ return 1.f/(1.f+__expf(-x)); }
__device__ __forceinline__ float siluf_(float x){ return x/(1.f+__expf(-x)); }
__device__ __forceinline__ float fbits(unsigned int b){ union{unsigned int i; float f;} c; c.i=b; return c.f; }
__device__ __forceinline__ unsigned short f2bf(float f){
  union{float f; unsigned int i;} c; c.f=f;
  unsigned int r = c.i + 0x7FFFu + ((c.i>>16)&1u);   // RNE
  return (unsigned short)(r>>16);
}
__device__ __forceinline__ float bf2f(unsigned short u){ return fbits(((unsigned int)u)<<16); }

__device__ __forceinline__ void load8(const float* __restrict__ p, float* d){
  float4 a = *(const float4*)p; float4 b = *(const float4*)(p+4);
  d[0]=a.x; d[1]=a.y; d[2]=a.z; d[3]=a.w; d[4]=b.x; d[5]=b.y; d[6]=b.z; d[7]=b.w;
}
__device__ __forceinline__ void load8(const bf16_t* __restrict__ p, float* d){
  uint4 u = *(const uint4*)p;
  d[0]=fbits(u.x<<16); d[1]=fbits(u.x&0xFFFF0000u);
  d[2]=fbits(u.y<<16); d[3]=fbits(u.y&0xFFFF0000u);
  d[4]=fbits(u.z<<16); d[5]=fbits(u.z&0xFFFF0000u);
  d[6]=fbits(u.w<<16); d[7]=fbits(u.w&0xFFFF0000u);
}
__device__ __forceinline__ void store8bf(bf16_t* p, const float* v){
  uint4 s;
  s.x = (unsigned int)f2bf(v[0]) | ((unsigned int)f2bf(v[1])<<16);
  s.y = (unsigned int)f2bf(v[2]) | ((unsigned int)f2bf(v[3])<<16);
  s.z = (unsigned int)f2bf(v[4]) | ((unsigned int)f2bf(v[5])<<16);
  s.w = (unsigned int)f2bf(v[6]) | ((unsigned int)f2bf(v[7])<<16);
  *(uint4*)p = s;
}

// async global(16B/lane) -> LDS, wave-uniform LDS base + lane*16
__device__ __forceinline__ void glds16(const void* g, void* l) {
  __builtin_amdgcn_global_load_lds(
      (const __attribute__((address_space(1))) unsigned int*)g,
      (__attribute__((address_space(3))) unsigned int*)l, 16, 0, 0);
}

// ---------------------------------------------------------------------------
// All three weight transposes in one launch. W (K x N fp32) -> Wt (N x K bf16)
// ---------------------------------------------------------------------------
__global__ __launch_bounds__(256) void transpose_all_kernel(
    const float* __restrict__ Wv, const float* __restrict__ Wmx,
    const float* __restrict__ Wh, bf16_t* __restrict__ Wvt,
    bf16_t* __restrict__ Wmxt, bf16_t* __restrict__ Wht)
{
  __shared__ float t[32][33];
  int blk = blockIdx.x;
  const float* W; bf16_t* Wt; int K, N, bx, by;
  if (blk < 512)       { W=Wv;  Wt=Wvt;  K=512;  N=1024; bx=blk&31;  by=blk>>5; }
  else if (blk < 1600) { blk-=512;  W=Wmx; Wt=Wmxt; K=512;  N=2176; bx=blk%68; by=blk/68; }
  else                 { blk-=1600; W=Wh;  Wt=Wht;  K=1024; N=512;  bx=blk&15; by=blk>>4; }
  int lx = threadIdx.x & 31, ly = threadIdx.x >> 5;
  #pragma unroll
  for (int i = 0; i < 32; i += 8)
    t[ly+i][lx] = W[(size_t)(by*32+ly+i)*N + bx*32 + lx];
  __syncthreads();
  #pragma unroll
  for (int i = 0; i < 32; i += 8)
    Wt[(size_t)(bx*32+ly+i)*K + by*32 + lx] = f2bf(t[lx][ly+i]);
}

// ---------------------------------------------------------------------------
// EMA segmented scan, SLEN=64, NSEG=32. Chains c = b*512+d (8192).
// Backward scan uses bf16-rounded x kept in registers (no xb re-read).
// ---------------------------------------------------------------------------
__global__ __launch_bounds__(256) void ema_carry_kernel(
    const float* __restrict__ x, const float* __restrict__ delta,
    const float* __restrict__ alpha, bf16_t* __restrict__ xb,
    float* __restrict__ carry)
{
  int idx = blockIdx.x*256 + threadIdx.x;      // 0..262143
  int d = idx & 511, c = idx & 8191, s = idx >> 13;   // s in 0..31
  float qf0 = 1.f - sigmoidf_(delta[d*2+0])*sigmoidf_(alpha[d*2+0]);
  float qf1 = 1.f - sigmoidf_(delta[d*2+1])*sigmoidf_(alpha[d*2+1]);
  int dd = d + 512;
  float qb0 = 1.f - sigmoidf_(delta[dd*2+0])*sigmoidf_(alpha[dd*2+0]);
  float qb1 = 1.f - sigmoidf_(delta[dd*2+1])*sigmoidf_(alpha[dd*2+1]);
  size_t off = (size_t)s*SLEN*CHAINS + c;
  float xr[SLEN];
  float h0=0.f, h1=0.f;
  #pragma unroll
  for (int t = 0; t < SLEN; ++t) {
    size_t a = off + (size_t)t*CHAINS;
    float xv = x[a];
    unsigned short xv16 = f2bf(xv);
    xb[a] = xv16;
    xr[t] = bf2f(xv16);
    h0 = fmaf(qf0, h0, xv); h1 = fmaf(qf1, h1, xv);
  }
  float g0=0.f, g1=0.f;
  #pragma unroll
  for (int t = SLEN-1; t >= 0; --t) {
    float xv = xr[t];
    g0 = fmaf(qb0, g0, xv); g1 = fmaf(qb1, g1, xv);
  }
  carry[(size_t)s*CHAINS + c]              = h0;
  carry[(size_t)s*CHAINS + c + 262144]     = h1;
  carry[(size_t)s*CHAINS + c + 524288]     = g0;
  carry[(size_t)s*CHAINS + c + 786432]     = g1;
}

__global__ __launch_bounds__(256) void ema_combine_kernel(
    const float* __restrict__ delta, const float* __restrict__ alpha,
    float* __restrict__ carry)
{
  int c = blockIdx.x*256 + threadIdx.x;   // 0..8191
  int d = c & 511;
  float qf0 = 1.f - sigmoidf_(delta[d*2+0])*sigmoidf_(alpha[d*2+0]);
  float qf1 = 1.f - sigmoidf_(delta[d*2+1])*sigmoidf_(alpha[d*2+1]);
  int dd = d + 512;
  float qb0 = 1.f - sigmoidf_(delta[dd*2+0])*sigmoidf_(alpha[dd*2+0]);
  float qb1 = 1.f - sigmoidf_(delta[dd*2+1])*sigmoidf_(alpha[dd*2+1]);
  float df0=qf0, df1=qf1, db0=qb0, db1=qb1;
  #pragma unroll
  for (int i = 0; i < 6; ++i) { df0*=df0; df1*=df1; db0*=db0; db1*=db1; }  // q^64
  float h0=0.f, h1=0.f;
  for (int s = 0; s < NSEG; ++s) {
    size_t a = (size_t)s*CHAINS + c;
    float t0 = carry[a], t1 = carry[a+262144];
    carry[a] = h0; carry[a+262144] = h1;
    h0 = fmaf(df0, h0, t0); h1 = fmaf(df1, h1, t1);
  }
  float g0=0.f, g1=0.f;
  for (int s = NSEG-1; s >= 0; --s) {
    size_t a = (size_t)s*CHAINS + c;
    float t0 = carry[a+524288], t1 = carry[a+786432];
    carry[a+524288] = g0; carry[a+786432] = g1;
    g0 = fmaf(db0, g0, t0); g1 = fmaf(db1, g1, t1);
  }
}

__global__ __launch_bounds__(256) void ema_apply_kernel(
    const bf16_t* __restrict__ xb, const float* __restrict__ delta,
    const float* __restrict__ alpha, const float* __restrict__ beta,
    const float* __restrict__ gamma, const float* __restrict__ omega,
    const float* __restrict__ carry, bf16_t* __restrict__ mx)
{
  int idx = blockIdx.x*256 + threadIdx.x;
  int d = idx & 511, c = idx & 8191, s = idx >> 13;
  const float rs = 0.70710678118654752f;
  float pf0 = sigmoidf_(delta[d*2+0]), pf1 = sigmoidf_(delta[d*2+1]);
  float qf0 = 1.f - pf0*sigmoidf_(alpha[d*2+0]);
  float qf1 = 1.f - pf1*sigmoidf_(alpha[d*2+1]);
  float cf0 = pf0*beta[d*2+0]*gamma[d*2+0]*rs;
  float cf1 = pf1*beta[d*2+1]*gamma[d*2+1]*rs;
  int dd = d + 512;
  float pb0 = sigmoidf_(delta[dd*2+0]), pb1 = sigmoidf_(delta[dd*2+1]);
  float qb0 = 1.f - pb0*sigmoidf_(alpha[dd*2+0]);
  float qb1 = 1.f - pb1*sigmoidf_(alpha[dd*2+1]);
  float cb0 = pb0*beta[dd*2+0]*gamma[dd*2+0]*rs;
  float cb1 = pb1*beta[dd*2+1]*gamma[dd*2+1]*rs;
  float om = omega[d];
  size_t off = (size_t)s*SLEN*CHAINS + c;
  float h0 = carry[(size_t)s*CHAINS + c];
  float h1 = carry[(size_t)s*CHAINS + c + 262144];
  float yv[SLEN];
  #pragma unroll
  for (int t = 0; t < SLEN; ++t) {
    float xv = bf2f(xb[off + (size_t)t*CHAINS]);
    h0 = fmaf(qf0, h0, xv); h1 = fmaf(qf1, h1, xv);
    yv[t] = fmaf(cf0, h0, cf1*h1);
  }
  float g0 = carry[(size_t)s*CHAINS + c + 524288];
  float g1 = carry[(size_t)s*CHAINS + c + 786432];
  #pragma unroll
  for (int t = SLEN-1; t >= 0; --t) {
    size_t a = off + (size_t)t*CHAINS;
    float xv = bf2f(xb[a]);
    g0 = fmaf(qb0, g0, xv); g1 = fmaf(qb1, g1, xv);
    float sv = yv[t] + fmaf(cb0, g0, cb1*g1) + xv*om;
    mx[a] = f2bf(siluf_(sv));
  }
}

// ===========================================================================
// Shared MFMA K-loop core (round-7 verified): BM=128 x BN=64 tile, acc[4][2],
// single-buffer BK=64, XOR-swizzled LDS. 24576 B -> 6 blocks/CU.
// ===========================================================================
#define GEMM_SMEM                                                            \
  __shared__ __align__(16) char smem[24576];                                 \
  bf16_t* As = (bf16_t*)smem;            /* 128x64 */                        \
  bf16_t* Bs = (bf16_t*)(smem + 16384);  /* 64x64  */                        \
  bf16_t* Cs = (bf16_t*)smem;            /* 128x72, reused after K-loop */

#define GEMM_PROLOG(Aptr, Bptr, Kdim)                                        \
  int tid = threadIdx.x;                                                     \
  int wave = tid >> 6, lane = tid & 63;                                      \
  int lrow = lane >> 3, lchunk = ((lane & 7) - lrow) & 7;                    \
  const bf16_t* Ag = (Aptr) + (size_t)(wave*32 + lrow)*(Kdim) + lchunk*8;    \
  const bf16_t* Bg = (Bptr) + (size_t)(wave*16 + lrow)*(Kdim) + lchunk*8;    \
  int wm = wave >> 1, wn = wave & 1;                                         \
  int fr = lane & 15, fq = lane >> 4;                                        \
  f32x4 acc[4][2];                                                           \
  _Pragma("unroll") for (int i = 0; i < 4; ++i)                              \
    _Pragma("unroll") for (int j = 0; j < 2; ++j)                            \
      acc[i][j] = (f32x4){0.f,0.f,0.f,0.f};

#define GEMM_KLOOP(Kdim)                                                     \
  for (int k0 = 0; k0 < (Kdim); k0 += 64) {                                  \
    __syncthreads();                                                         \
    _Pragma("unroll") for (int j = 0; j < 4; ++j)                            \
      glds16(Ag + (size_t)j*8*(Kdim) + k0, As + (wave*32 + j*8)*64);         \
    _Pragma("unroll") for (int j = 0; j < 2; ++j)                            \
      glds16(Bg + (size_t)j*8*(Kdim) + k0, Bs + (wave*16 + j*8)*64);         \
    __syncthreads();                                                         \
    _Pragma("unroll") for (int kk = 0; kk < 2; ++kk) {                       \
      short8 af[4], bfr[2];                                                  \
      _Pragma("unroll") for (int mi = 0; mi < 4; ++mi) {                     \
        int R = wm*64 + mi*16 + fr;                                          \
        af[mi] = *(const short8*)&As[R*64 + (((kk<<2)+fq+R)&7)*8];           \
      }                                                                      \
      _Pragma("unroll") for (int ni = 0; ni < 2; ++ni) {                     \
        int R = wn*32 + ni*16 + fr;                                          \
        bfr[ni] = *(const short8*)&Bs[R*64 + (((kk<<2)+fq+R)&7)*8];          \
      }                                                                      \
      _Pragma("unroll") for (int mi = 0; mi < 4; ++mi)                       \
        _Pragma("unroll") for (int ni = 0; ni < 2; ++ni)                     \
          acc[mi][ni] = __builtin_amdgcn_mfma_f32_16x16x32_bf16(             \
              af[mi], bfr[ni], acc[mi][ni], 0, 0, 0);                        \
    }                                                                        \
  }

// ---------------------------------------------------------------------------
// Generic MFMA bf16 GEMM: C(bf16, MxN) = act(A @ Bt^T + bias [+ Add])
// 128x64 tile, XCD-swizzled 1-D grid. Epilogue repacks via LDS, dwordx4.
// ---------------------------------------------------------------------------
__global__ __launch_bounds__(256, 6) void mfma_gemm_kernel(
    const bf16_t* __restrict__ A, const bf16_t* __restrict__ Bt,
    const float* __restrict__ bias, const bf16_t* __restrict__ Add, int addLd,
    bf16_t* __restrict__ C, int N, int K, int nT, int act)
{
  GEMM_SMEM
  int flat = blockIdx.x;
  int xcd = flat & 7, g = flat >> 3;
  int mT8 = (int)(gridDim.x / (unsigned)nT) >> 3;
  int mt = xcd*mT8 + g / nT;
  int nt = g % nT;
  int m0 = mt*128, n0 = nt*64;
  GEMM_PROLOG(A + (size_t)m0*K, Bt + (size_t)n0*K, K)
  GEMM_KLOOP(K)
  __syncthreads();
  #pragma unroll
  for (int ni = 0; ni < 2; ++ni) {
    int cl = wn*32 + ni*16 + fr;
    int gn = n0 + cl;
    float bv = bias[gn];
    #pragma unroll
    for (int mi = 0; mi < 4; ++mi) {
      #pragma unroll
      for (int r = 0; r < 4; ++r) {
        int ml = wm*64 + mi*16 + fq*4 + r;
        float val = acc[mi][ni][r] + bv;
        if (Add) val += bf2f(Add[(size_t)(m0+ml)*addLd + gn]);
        if (act == 1) val = siluf_(val);
        Cs[ml*72 + cl] = f2bf(val);
      }
    }
  }
  __syncthreads();
  int row = tid >> 1, c0 = (tid & 1)*32;
  #pragma unroll
  for (int q = 0; q < 4; ++q)
    *(uint4*)(C + (size_t)(m0+row)*N + n0 + c0 + q*8) =
        *(const uint4*)&Cs[row*72 + c0 + q*8];
}

// ---------------------------------------------------------------------------
// Wv GEMM variant: vt layout [blk=b*16+nchunk][kc=0..15][h=0..1023][e=0..7],
// k = kc*8+e (K=128 per chunk). Tile 128x64: rows gm = m0 + kk*16 + b with
// l = mt*8+kk -> nchunk = mt>>4, kc = mt&15, e = kk. Each thread writes
// 16B of 8 consecutive e at consecutive h -> 256B-contiguous segments.
// ---------------------------------------------------------------------------
__global__ __launch_bounds__(256, 6) void mfma_gemm_v_kernel(
    const bf16_t* __restrict__ A, const bf16_t* __restrict__ Bt,
    const float* __restrict__ bias, bf16_t* __restrict__ vt, int nT, int K)
{
  GEMM_SMEM
  int flat = blockIdx.x;
  int xcd = flat & 7, g = flat >> 3;
  int mT8 = (int)(gridDim.x / (unsigned)nT) >> 3;
  int mt = xcd*mT8 + g / nT;
  int nt = g % nT;
  int m0 = mt*128, n0 = nt*64;
  GEMM_PROLOG(A + (size_t)m0*K, Bt + (size_t)n0*K, K)
  GEMM_KLOOP(K)
  __syncthreads();
  #pragma unroll
  for (int ni = 0; ni < 2; ++ni) {
    int cl = wn*32 + ni*16 + fr;
    float bv = bias[n0 + cl];
    #pragma unroll
    for (int mi = 0; mi < 4; ++mi) {
      #pragma unroll
      for (int r = 0; r < 4; ++r) {
        int ml = wm*64 + mi*16 + fq*4 + r;
        Cs[ml*72 + cl] = f2bf(siluf_(acc[mi][ni][r] + bv));
      }
    }
  }
  __syncthreads();
  // thread: b = tid>>4, hl = (tid&15) + j*16 (j 0..3); writes 8 kk as 16B.
  {
    int b = tid >> 4;
    int nchunk = mt >> 4, kc = mt & 15;
    size_t ob = ((size_t)((b*NC + nchunk)*16 + kc))*8192;  // element base
    #pragma unroll
    for (int j = 0; j < 4; ++j) {
      int hl = (tid & 15) + j*16;
      uint4 s;
      s.x = (unsigned int)Cs[(0*16 + b)*72 + hl] |
            ((unsigned int)Cs[(1*16 + b)*72 + hl] << 16);
      s.y = (unsigned int)Cs[(2*16 + b)*72 + hl] |
            ((unsigned int)Cs[(3*16 + b)*72 + hl] << 16);
      s.z = (unsigned int)Cs[(4*16 + b)*72 + hl] |
            ((unsigned int)Cs[(5*16 + b)*72 + hl] << 16);
      s.w = (unsigned int)Cs[(6*16 + b)*72 + hl] |
            ((unsigned int)Cs[(7*16 + b)*72 + hl] << 16);
      *(uint4*)&vt[ob + (size_t)(n0 + hl)*8] = s;
    }
  }
}

// ---------------------------------------------------------------------------
// Attention scores via MFMA + softmax. One block per (b,n).
// Writes fp32 probs to d_out AND bf16 probs (p_bf) for the PV GEMM.
// ---------------------------------------------------------------------------
__global__ __launch_bounds__(256) void attn_scores_mfma_kernel(
    const bf16_t* __restrict__ base, const float* __restrict__ qkg,
    const float* __restrict__ qkb, const float* __restrict__ rpb,
    float* __restrict__ attn_out, bf16_t* __restrict__ p_bf)
{
  __shared__ bf16_t qs[128*136];
  __shared__ bf16_t ks[128*136];
  int blk = blockIdx.x;            // b*16 + n
  int b = blk >> 4, n = blk & 15;
  int tid = threadIdx.x;
  {
    int r = tid >> 1, z0 = (tid & 1)*64;
    size_t rowoff = ((size_t)((n*128 + r)*B_DIM + b))*BASE_N + 512 + z0;
    #pragma unroll
    for (int cchunk = 0; cchunk < 8; ++cchunk) {
      float t8[8], qv[8], kv[8];
      load8(base + rowoff + cchunk*8, t8);
      #pragma unroll
      for (int j = 0; j < 8; ++j) {
        int z = z0 + cchunk*8 + j;
        float zs = siluf_(t8[j]);
        qv[j] = fmaf(zs, qkg[z],     qkb[z]);
        kv[j] = fmaf(zs, qkg[128+z], qkb[128+z]);
      }
      store8bf(&qs[r*136 + z0 + cchunk*8], qv);
      store8bf(&ks[r*136 + z0 + cchunk*8], kv);
    }
  }
  __syncthreads();
  int wave = tid >> 6, lane = tid & 63;
  int fr = lane & 15, fq = lane >> 4;
  f32x4 acc[2][8];
  #pragma unroll
  for (int i = 0; i < 2; ++i)
    #pragma unroll
    for (int j = 0; j < 8; ++j)
      acc[i][j] = (f32x4){0.f,0.f,0.f,0.f};
  #pragma unroll
  for (int kk = 0; kk < 4; ++kk) {
    short8 af[2], bfr[8];
    #pragma unroll
    for (int mi = 0; mi < 2; ++mi)
      af[mi] = *(const short8*)&qs[(wave*32 + mi*16 + fr)*136 + kk*32 + fq*8];
    #pragma unroll
    for (int ni = 0; ni < 8; ++ni)
      bfr[ni] = *(const short8*)&ks[(ni*16 + fr)*136 + kk*32 + fq*8];
    #pragma unroll
    for (int mi = 0; mi < 2; ++mi)
      #pragma unroll
      for (int ni = 0; ni < 8; ++ni)
        acc[mi][ni] = __builtin_amdgcn_mfma_f32_16x16x32_bf16(
            af[mi], bfr[ni], acc[mi][ni], 0, 0, 0);
  }
  const float scale = 0.08838834764831845f;  // 1/sqrt(128)
  float mrow[2][4], srow[2][4];
  #pragma unroll
  for (int mi = 0; mi < 2; ++mi)
    #pragma unroll
    for (int r = 0; r < 4; ++r) mrow[mi][r] = -1e30f;
  #pragma unroll
  for (int mi = 0; mi < 2; ++mi)
    #pragma unroll
    for (int ni = 0; ni < 8; ++ni)
      #pragma unroll
      for (int r = 0; r < 4; ++r) {
        int i = wave*32 + mi*16 + fq*4 + r;
        int j = ni*16 + fr;
        float v = fmaf(acc[mi][ni][r], scale, rpb[1023 + j - i]);
        acc[mi][ni][r] = v;
        mrow[mi][r] = fmaxf(mrow[mi][r], v);
      }
  #pragma unroll
  for (int mi = 0; mi < 2; ++mi)
    #pragma unroll
    for (int r = 0; r < 4; ++r) {
      float m = mrow[mi][r];
      m = fmaxf(m, __shfl_xor(m, 1));
      m = fmaxf(m, __shfl_xor(m, 2));
      m = fmaxf(m, __shfl_xor(m, 4));
      m = fmaxf(m, __shfl_xor(m, 8));
      mrow[mi][r] = m;
      srow[mi][r] = 0.f;
    }
  #pragma unroll
  for (int mi = 0; mi < 2; ++mi)
    #pragma unroll
    for (int ni = 0; ni < 8; ++ni)
      #pragma unroll
      for (int r = 0; r < 4; ++r) {
        float e = __expf(acc[mi][ni][r] - mrow[mi][r]);
        acc[mi][ni][r] = e;
        srow[mi][r] += e;
      }
  #pragma unroll
  for (int mi = 0; mi < 2; ++mi)
    #pragma unroll
    for (int r = 0; r < 4; ++r) {
      float s = srow[mi][r];
      s += __shfl_xor(s, 1);
      s += __shfl_xor(s, 2);
      s += __shfl_xor(s, 4);
      s += __shfl_xor(s, 8);
      srow[mi][r] = 1.f/s;
    }
  #pragma unroll
  for (int mi = 0; mi < 2; ++mi)
    #pragma unroll
    for (int r = 0; r < 4; ++r) {
      int i = wave*32 + mi*16 + fq*4 + r;
      size_t o = ((size_t)blk*128 + i)*128;
      #pragma unroll
      for (int ni = 0; ni < 8; ++ni) {
        float val = acc[mi][ni][r]*srow[mi][r];
        attn_out[o + ni*16 + fr] = val;
        p_bf[o + ni*16 + fr] = f2bf(val);
      }
    }
}

// ---------------------------------------------------------------------------
// hr = (P @ V) * silu(r) via MFMA. Grid flat: blk*16 + htile (64-wide).
// Custom B staging for the [blk][kc][h][8] vt layout: global chunk c of row h
// lives at blk*131072 + c*8192 + h*8; same glds16 slot/swizzle scheme as the
// GEMM core (slot relation (c + (row&7))&7 preserved on store and read).
// ---------------------------------------------------------------------------
__global__ __launch_bounds__(256, 6) void attn_pv_kernel(
    const bf16_t* __restrict__ p_bf, const bf16_t* __restrict__ vt,
    const bf16_t* __restrict__ base, bf16_t* __restrict__ hr)
{
  GEMM_SMEM
  int blk = blockIdx.x >> 4, ht = blockIdx.x & 15;
  int b = blk >> 4, n = blk & 15;
  const int K = 128;
  int tid = threadIdx.x;
  int wave = tid >> 6, lane = tid & 63;
  int lrow = lane >> 3, lchunk = ((lane & 7) - lrow) & 7;
  const bf16_t* Ag = p_bf + (size_t)blk*16384
                     + (size_t)(wave*32 + lrow)*K + lchunk*8;
  const bf16_t* Bg = vt + (size_t)blk*131072 + (size_t)lchunk*8192
                     + (size_t)(ht*64 + wave*16 + lrow)*8;
  int wm = wave >> 1, wn = wave & 1;
  int fr = lane & 15, fq = lane >> 4;
  f32x4 acc[4][2];
  #pragma unroll
  for (int i = 0; i < 4; ++i)
    #pragma unroll
    for (int j = 0; j < 2; ++j)
      acc[i][j] = (f32x4){0.f,0.f,0.f,0.f};
  for (int k0 = 0; k0 < K; k0 += 64) {
    __syncthreads();
    #pragma unroll
    for (int j = 0; j < 4; ++j)
      glds16(Ag + (size_t)j*8*K + k0, As + (wave*32 + j*8)*64);
    #pragma unroll
    for (int j = 0; j < 2; ++j)
      glds16(Bg + (size_t)(k0 >> 3)*8192 + j*64, Bs + (wave*16 + j*8)*64);
    __syncthreads();
    #pragma unroll
    for (int kk = 0; kk < 2; ++kk) {
      short8 af[4], bfr[2];
      #pragma unroll
      for (int mi = 0; mi < 4; ++mi) {
        int R = wm*64 + mi*16 + fr;
        af[mi] = *(const short8*)&As[R*64 + (((kk<<2)+fq+R)&7)*8];
      }
      #pragma unroll
      for (int ni = 0; ni < 2; ++ni) {
        int R = wn*32 + ni*16 + fr;
        bfr[ni] = *(const short8*)&Bs[R*64 + (((kk<<2)+fq+R)&7)*8];
      }
      #pragma unroll
      for (int mi = 0; mi < 4; ++mi)
        #pragma unroll
        for (int ni = 0; ni < 2; ++ni)
          acc[mi][ni] = __builtin_amdgcn_mfma_f32_16x16x32_bf16(
              af[mi], bfr[ni], acc[mi][ni], 0, 0, 0);
    }
  }
  __syncthreads();
  #pragma unroll
  for (int ni = 0; ni < 2; ++ni) {
    int cl = wn*32 + ni*16 + fr;
    int hg = ht*64 + cl;
    #pragma unroll
    for (int mi = 0; mi < 4; ++mi) {
      #pragma unroll
      for (int r = 0; r < 4; ++r) {
        int ml = wm*64 + mi*16 + fq*4 + r;
        size_t rowg = (size_t)((n*128 + ml)*B_DIM + b);
        float rg = bf2f(base[rowg*BASE_N + 640 + hg]);
        Cs[ml*72 + cl] = f2bf(acc[mi][ni][r]*siluf_(rg));
      }
    }
  }
  __syncthreads();
  int row = tid >> 1, c0 = (tid & 1)*32;
  size_t rowg = (size_t)((n*128 + row)*B_DIM + b);
  #pragma unroll
  for (int q = 0; q < 4; ++q)
    *(uint4*)(hr + rowg*H_DIM + ht*64 + c0 + q*8) =
        *(const uint4*)&Cs[row*72 + c0 + q*8];
}

// ---------------------------------------------------------------------------
// out = residual + u*(h2 - residual), then RMSNorm * norm_scalar.
// 256 threads = 4 rows per block (one wave per row).
// ---------------------------------------------------------------------------
__global__ __launch_bounds__(256) void final_kernel(
    const float* __restrict__ x, const bf16_t* __restrict__ h2,
    const bf16_t* __restrict__ base, const float* __restrict__ ns,
    float* __restrict__ out)
{
  int row = blockIdx.x*4 + (threadIdx.x >> 6);
  int t = threadIdx.x & 63;
  size_t ro = (size_t)row*D_DIM + t*8;
  float xv[8]; load8(x + ro, xv);
  float hv[8]; load8(h2 + ro, hv);
  float uv[8]; load8(base + (size_t)row*BASE_N + t*8, uv);
  float o[8];
  float ss = 0.f;
  #pragma unroll
  for (int i = 0; i < 8; ++i) {
    float u = sigmoidf_(uv[i]);
    o[i] = xv[i] + u*(hv[i] - xv[i]);
    ss += o[i]*o[i];
  }
  #pragma unroll
  for (int m = 1; m < 64; m <<= 1) ss += __shfl_xor(ss, m);
  float inv = rsqrtf(ss*(1.f/(float)D_DIM) + 1e-6f) * ns[0];
  float4 r0, r1;
  r0.x = o[0]*inv; r0.y = o[1]*inv; r0.z = o[2]*inv; r0.w = o[3]*inv;
  r1.x = o[4]*inv; r1.y = o[5]*inv; r1.z = o[6]*inv; r1.w = o[7]*inv;
  *(float4*)(out + ro) = r0;
  *(float4*)(out + ro + 4) = r1;
}

// ---------------------------------------------------------------------------
extern "C" void kernel_launch(void* const* d_in, const int* in_sizes, int n_in,
                              void* d_out, int out_size, void* d_ws, size_t ws_size,
                              hipStream_t stream)
{
  const float* x     = (const float*)d_in[0];
  const float* delta = (const float*)d_in[1];
  const float* alpha = (const float*)d_in[2];
  const float* beta  = (const float*)d_in[3];
  const float* gamma = (const float*)d_in[4];
  const float* omega = (const float*)d_in[5];
  const float* Wv    = (const float*)d_in[6];
  const float* bv    = (const float*)d_in[7];
  const float* Wmx   = (const float*)d_in[8];
  const float* bmx   = (const float*)d_in[9];
  const float* Wh    = (const float*)d_in[10];
  const float* bh    = (const float*)d_in[11];
  const float* qkg   = (const float*)d_in[12];
  const float* qkb   = (const float*)d_in[13];
  const float* rpb   = (const float*)d_in[14];
  const float* ns    = (const float*)d_in[15];

  float* out  = (float*)d_out;
  float* attn = out + (size_t)ROWS*D_DIM;

  char* outb = (char*)d_out;
  bf16_t* x_bf  = (bf16_t*)outb;            // dead after Wv GEMM
  bf16_t* p_bf  = (bf16_t*)outb;            // written by scores, read by PV
  bf16_t* Wv_t  = (bf16_t*)(outb + 33554432ull);
  bf16_t* Wmx_t = (bf16_t*)(outb + 34603008ull);
  bf16_t* Wh_t  = (bf16_t*)(outb + 36831232ull);

  const size_t WS_NEED = 310378496ull;
  if (ws_size < WS_NEED) return;
  char* wsb = (char*)d_ws;
  bf16_t* mx_bf   = (bf16_t*)(wsb);
  bf16_t* vt      = (bf16_t*)(wsb + 33554432ull);
  bf16_t* base_bf = (bf16_t*)(wsb + 100663296ull);
  bf16_t* hr_bf   = (bf16_t*)(wsb + 243269632ull);
  float*  carry   = (float*)(wsb + 100663296ull);
  bf16_t* h2_bf   = mx_bf;

  // weight transposes (one launch)
  transpose_all_kernel<<<2112, 256, 0, stream>>>(Wv, Wmx, Wh, Wv_t, Wmx_t, Wh_t);
  // EMA segmented scan (also produces x_bf)
  ema_carry_kernel<<<1024, 256, 0, stream>>>(x, delta, alpha, x_bf, carry);
  ema_combine_kernel<<<32, 256, 0, stream>>>(delta, alpha, carry);
  ema_apply_kernel<<<1024, 256, 0, stream>>>(x_bf, delta, alpha, beta, gamma,
                                             omega, carry, mx_bf);
  // vt = silu(x @ Wv + bv), [blk][kc][h][8] layout (N=1024 -> 16 tiles of 64)
  mfma_gemm_v_kernel<<<4096, 256, 0, stream>>>(x_bf, Wv_t, bv, vt, 16, D_DIM);
  // base = mx @ Wmx + bmx (N=2176 -> 34 tiles of 64)
  mfma_gemm_kernel<<<8704, 256, 0, stream>>>(
      mx_bf, Wmx_t, bmx, nullptr, 0, base_bf, BASE_N, D_DIM, 34, 0);
  // attn probs (fp32 -> d_out, bf16 -> p_bf)
  attn_scores_mfma_kernel<<<B_DIM*NC, 256, 0, stream>>>(
      base_bf, qkg, qkb, rpb, attn, p_bf);
  // hr = (P @ V) * silu(r)  (16 h-tiles of 64)
  attn_pv_kernel<<<4096, 256, 0, stream>>>(p_bf, vt, base_bf, hr_bf);
  // h2 = silu(hx + hr @ Wh + bh) (N=512 -> 8 tiles of 64)
  mfma_gemm_kernel<<<2048, 256, 0, stream>>>(
      hr_bf, Wh_t, bh, base_bf + 1664, BASE_N, h2_bf, D_DIM, H_DIM, 8, 1);
  // gated residual + RMSNorm
  final_kernel<<<ROWS/4, 256, 0, stream>>>(x, h2_bf, base_bf, ns, out);
}

// Round 10
// 575.033 us; speedup vs baseline: 1.1060x; 1.0163x over previous
//
#include <hip/hip_runtime.h>
#include <math.h>

// Problem dims
#define L_DIM 2048
#define B_DIM 16
#define D_DIM 512
#define H_DIM 1024
#define Z_DIM 128
#define NC    16
#define BASE_N 2176            // Z + H + 2D
#define ROWS  (L_DIM*B_DIM)    // 32768
#define NSEG  32
#define SLEN  64
#define CHAINS 8192            // B*D

typedef unsigned short bf16_t;
typedef __attribute__((ext_vector_type(8))) short short8;
typedef __attribute__((ext_vector_type(4))) float f32x4;

__device__ __forceinline__ float sigmoidf_(float x){ return 1.f/(1.f+__expf(-x)); }
__device__ __forceinline__ float siluf_(float x){ return x/(1.f+__expf(-x)); }
__device__ __forceinline__ float fbits(unsigned int b){ union{unsigned int i; float f;} c; c.i=b; return c.f; }
__device__ __forceinline__ unsigned short f2bf(float f){
  union{float f; unsigned int i;} c; c.f=f;
  unsigned int r = c.i + 0x7FFFu + ((c.i>>16)&1u);   // RNE
  return (unsigned short)(r>>16);
}
__device__ __forceinline__ float bf2f(unsigned short u){ return fbits(((unsigned int)u)<<16); }

__device__ __forceinline__ void load8(const float* __restrict__ p, float* d){
  float4 a = *(const float4*)p; float4 b = *(const float4*)(p+4);
  d[0]=a.x; d[1]=a.y; d[2]=a.z; d[3]=a.w; d[4]=b.x; d[5]=b.y; d[6]=b.z; d[7]=b.w;
}
__device__ __forceinline__ void load8(const bf16_t* __restrict__ p, float* d){
  uint4 u = *(const uint4*)p;
  d[0]=fbits(u.x<<16); d[1]=fbits(u.x&0xFFFF0000u);
  d[2]=fbits(u.y<<16); d[3]=fbits(u.y&0xFFFF0000u);
  d[4]=fbits(u.z<<16); d[5]=fbits(u.z&0xFFFF0000u);
  d[6]=fbits(u.w<<16); d[7]=fbits(u.w&0xFFFF0000u);
}
__device__ __forceinline__ void store8bf(bf16_t* p, const float* v){
  uint4 s;
  s.x = (unsigned int)f2bf(v[0]) | ((unsigned int)f2bf(v[1])<<16);
  s.y = (unsigned int)f2bf(v[2]) | ((unsigned int)f2bf(v[3])<<16);
  s.z = (unsigned int)f2bf(v[4]) | ((unsigned int)f2bf(v[5])<<16);
  s.w = (unsigned int)f2bf(v[6]) | ((unsigned int)f2bf(v[7])<<16);
  *(uint4*)p = s;
}

// async global(16B/lane) -> LDS, wave-uniform LDS base + lane*16
__device__ __forceinline__ void glds16(const void* g, void* l) {
  __builtin_amdgcn_global_load_lds(
      (const __attribute__((address_space(1))) unsigned int*)g,
      (__attribute__((address_space(3))) unsigned int*)l, 16, 0, 0);
}

// ---------------------------------------------------------------------------
// All three weight transposes in one launch. W (K x N fp32) -> Wt (N x K bf16)
// ---------------------------------------------------------------------------
__global__ __launch_bounds__(256) void transpose_all_kernel(
    const float* __restrict__ Wv, const float* __restrict__ Wmx,
    const float* __restrict__ Wh, bf16_t* __restrict__ Wvt,
    bf16_t* __restrict__ Wmxt, bf16_t* __restrict__ Wht)
{
  __shared__ float t[32][33];
  int blk = blockIdx.x;
  const float* W; bf16_t* Wt; int K, N, bx, by;
  if (blk < 512)       { W=Wv;  Wt=Wvt;  K=512;  N=1024; bx=blk&31;  by=blk>>5; }
  else if (blk < 1600) { blk-=512;  W=Wmx; Wt=Wmxt; K=512;  N=2176; bx=blk%68; by=blk/68; }
  else                 { blk-=1600; W=Wh;  Wt=Wht;  K=1024; N=512;  bx=blk&15; by=blk>>4; }
  int lx = threadIdx.x & 31, ly = threadIdx.x >> 5;
  #pragma unroll
  for (int i = 0; i < 32; i += 8)
    t[ly+i][lx] = W[(size_t)(by*32+ly+i)*N + bx*32 + lx];
  __syncthreads();
  #pragma unroll
  for (int i = 0; i < 32; i += 8)
    Wt[(size_t)(bx*32+ly+i)*K + by*32 + lx] = f2bf(t[lx][ly+i]);
}

// ---------------------------------------------------------------------------
// EMA segmented scan, SLEN=64, NSEG=32. Chains c = b*512+d (8192).
// Backward scan uses bf16-rounded x kept in registers (no xb re-read).
// ---------------------------------------------------------------------------
__global__ __launch_bounds__(256) void ema_carry_kernel(
    const float* __restrict__ x, const float* __restrict__ delta,
    const float* __restrict__ alpha, bf16_t* __restrict__ xb,
    float* __restrict__ carry)
{
  int idx = blockIdx.x*256 + threadIdx.x;      // 0..262143
  int d = idx & 511, c = idx & 8191, s = idx >> 13;   // s in 0..31
  float qf0 = 1.f - sigmoidf_(delta[d*2+0])*sigmoidf_(alpha[d*2+0]);
  float qf1 = 1.f - sigmoidf_(delta[d*2+1])*sigmoidf_(alpha[d*2+1]);
  int dd = d + 512;
  float qb0 = 1.f - sigmoidf_(delta[dd*2+0])*sigmoidf_(alpha[dd*2+0]);
  float qb1 = 1.f - sigmoidf_(delta[dd*2+1])*sigmoidf_(alpha[dd*2+1]);
  size_t off = (size_t)s*SLEN*CHAINS + c;
  float xr[SLEN];
  float h0=0.f, h1=0.f;
  #pragma unroll
  for (int t = 0; t < SLEN; ++t) {
    size_t a = off + (size_t)t*CHAINS;
    float xv = x[a];
    unsigned short xv16 = f2bf(xv);
    xb[a] = xv16;
    xr[t] = bf2f(xv16);
    h0 = fmaf(qf0, h0, xv); h1 = fmaf(qf1, h1, xv);
  }
  float g0=0.f, g1=0.f;
  #pragma unroll
  for (int t = SLEN-1; t >= 0; --t) {
    float xv = xr[t];
    g0 = fmaf(qb0, g0, xv); g1 = fmaf(qb1, g1, xv);
  }
  carry[(size_t)s*CHAINS + c]              = h0;
  carry[(size_t)s*CHAINS + c + 262144]     = h1;
  carry[(size_t)s*CHAINS + c + 524288]     = g0;
  carry[(size_t)s*CHAINS + c + 786432]     = g1;
}

__global__ __launch_bounds__(256) void ema_combine_kernel(
    const float* __restrict__ delta, const float* __restrict__ alpha,
    float* __restrict__ carry)
{
  int c = blockIdx.x*256 + threadIdx.x;   // 0..8191
  int d = c & 511;
  float qf0 = 1.f - sigmoidf_(delta[d*2+0])*sigmoidf_(alpha[d*2+0]);
  float qf1 = 1.f - sigmoidf_(delta[d*2+1])*sigmoidf_(alpha[d*2+1]);
  int dd = d + 512;
  float qb0 = 1.f - sigmoidf_(delta[dd*2+0])*sigmoidf_(alpha[dd*2+0]);
  float qb1 = 1.f - sigmoidf_(delta[dd*2+1])*sigmoidf_(alpha[dd*2+1]);
  float df0=qf0, df1=qf1, db0=qb0, db1=qb1;
  #pragma unroll
  for (int i = 0; i < 6; ++i) { df0*=df0; df1*=df1; db0*=db0; db1*=db1; }  // q^64
  float h0=0.f, h1=0.f;
  for (int s = 0; s < NSEG; ++s) {
    size_t a = (size_t)s*CHAINS + c;
    float t0 = carry[a], t1 = carry[a+262144];
    carry[a] = h0; carry[a+262144] = h1;
    h0 = fmaf(df0, h0, t0); h1 = fmaf(df1, h1, t1);
  }
  float g0=0.f, g1=0.f;
  for (int s = NSEG-1; s >= 0; --s) {
    size_t a = (size_t)s*CHAINS + c;
    float t0 = carry[a+524288], t1 = carry[a+786432];
    carry[a+524288] = g0; carry[a+786432] = g1;
    g0 = fmaf(db0, g0, t0); g1 = fmaf(db1, g1, t1);
  }
}

__global__ __launch_bounds__(256) void ema_apply_kernel(
    const bf16_t* __restrict__ xb, const float* __restrict__ delta,
    const float* __restrict__ alpha, const float* __restrict__ beta,
    const float* __restrict__ gamma, const float* __restrict__ omega,
    const float* __restrict__ carry, bf16_t* __restrict__ mx)
{
  int idx = blockIdx.x*256 + threadIdx.x;
  int d = idx & 511, c = idx & 8191, s = idx >> 13;
  const float rs = 0.70710678118654752f;
  float pf0 = sigmoidf_(delta[d*2+0]), pf1 = sigmoidf_(delta[d*2+1]);
  float qf0 = 1.f - pf0*sigmoidf_(alpha[d*2+0]);
  float qf1 = 1.f - pf1*sigmoidf_(alpha[d*2+1]);
  float cf0 = pf0*beta[d*2+0]*gamma[d*2+0]*rs;
  float cf1 = pf1*beta[d*2+1]*gamma[d*2+1]*rs;
  int dd = d + 512;
  float pb0 = sigmoidf_(delta[dd*2+0]), pb1 = sigmoidf_(delta[dd*2+1]);
  float qb0 = 1.f - pb0*sigmoidf_(alpha[dd*2+0]);
  float qb1 = 1.f - pb1*sigmoidf_(alpha[dd*2+1]);
  float cb0 = pb0*beta[dd*2+0]*gamma[dd*2+0]*rs;
  float cb1 = pb1*beta[dd*2+1]*gamma[dd*2+1]*rs;
  float om = omega[d];
  size_t off = (size_t)s*SLEN*CHAINS + c;
  float h0 = carry[(size_t)s*CHAINS + c];
  float h1 = carry[(size_t)s*CHAINS + c + 262144];
  float yv[SLEN];
  #pragma unroll
  for (int t = 0; t < SLEN; ++t) {
    float xv = bf2f(xb[off + (size_t)t*CHAINS]);
    h0 = fmaf(qf0, h0, xv); h1 = fmaf(qf1, h1, xv);
    yv[t] = fmaf(cf0, h0, cf1*h1);
  }
  float g0 = carry[(size_t)s*CHAINS + c + 524288];
  float g1 = carry[(size_t)s*CHAINS + c + 786432];
  #pragma unroll
  for (int t = SLEN-1; t >= 0; --t) {
    size_t a = off + (size_t)t*CHAINS;
    float xv = bf2f(xb[a]);
    g0 = fmaf(qb0, g0, xv); g1 = fmaf(qb1, g1, xv);
    float sv = yv[t] + fmaf(cb0, g0, cb1*g1) + xv*om;
    mx[a] = f2bf(siluf_(sv));
  }
}

// ===========================================================================
// Shared MFMA K-loop core (round-7 verified): BM=128 x BN=64 tile, acc[4][2],
// single-buffer BK=64, XOR-swizzled LDS. 24576 B -> 6 blocks/CU.
// ===========================================================================
#define GEMM_SMEM                                                            \
  __shared__ __align__(16) char smem[24576];                                 \
  bf16_t* As = (bf16_t*)smem;            /* 128x64 */                        \
  bf16_t* Bs = (bf16_t*)(smem + 16384);  /* 64x64  */                        \
  bf16_t* Cs = (bf16_t*)smem;            /* 128x72, reused after K-loop */

#define GEMM_PROLOG(Aptr, Bptr, Kdim)                                        \
  int tid = threadIdx.x;                                                     \
  int wave = tid >> 6, lane = tid & 63;                                      \
  int lrow = lane >> 3, lchunk = ((lane & 7) - lrow) & 7;                    \
  const bf16_t* Ag = (Aptr) + (size_t)(wave*32 + lrow)*(Kdim) + lchunk*8;    \
  const bf16_t* Bg = (Bptr) + (size_t)(wave*16 + lrow)*(Kdim) + lchunk*8;    \
  int wm = wave >> 1, wn = wave & 1;                                         \
  int fr = lane & 15, fq = lane >> 4;                                        \
  f32x4 acc[4][2];                                                           \
  _Pragma("unroll") for (int i = 0; i < 4; ++i)                              \
    _Pragma("unroll") for (int j = 0; j < 2; ++j)                            \
      acc[i][j] = (f32x4){0.f,0.f,0.f,0.f};

#define GEMM_KLOOP(Kdim)                                                     \
  for (int k0 = 0; k0 < (Kdim); k0 += 64) {                                  \
    __syncthreads();                                                         \
    _Pragma("unroll") for (int j = 0; j < 4; ++j)                            \
      glds16(Ag + (size_t)j*8*(Kdim) + k0, As + (wave*32 + j*8)*64);         \
    _Pragma("unroll") for (int j = 0; j < 2; ++j)                            \
      glds16(Bg + (size_t)j*8*(Kdim) + k0, Bs + (wave*16 + j*8)*64);         \
    __syncthreads();                                                         \
    _Pragma("unroll") for (int kk = 0; kk < 2; ++kk) {                       \
      short8 af[4], bfr[2];                                                  \
      _Pragma("unroll") for (int mi = 0; mi < 4; ++mi) {                     \
        int R = wm*64 + mi*16 + fr;                                          \
        af[mi] = *(const short8*)&As[R*64 + (((kk<<2)+fq+R)&7)*8];           \
      }                                                                      \
      _Pragma("unroll") for (int ni = 0; ni < 2; ++ni) {                     \
        int R = wn*32 + ni*16 + fr;                                          \
        bfr[ni] = *(const short8*)&Bs[R*64 + (((kk<<2)+fq+R)&7)*8];          \
      }                                                                      \
      _Pragma("unroll") for (int mi = 0; mi < 4; ++mi)                       \
        _Pragma("unroll") for (int ni = 0; ni < 2; ++ni)                     \
          acc[mi][ni] = __builtin_amdgcn_mfma_f32_16x16x32_bf16(             \
              af[mi], bfr[ni], acc[mi][ni], 0, 0, 0);                        \
    }                                                                        \
  }

// ---------------------------------------------------------------------------
// Generic MFMA bf16 GEMM: C(bf16, MxN) = act(A @ Bt^T + bias [+ Add])
// 128x64 tile, XCD-swizzled 1-D grid. Epilogue repacks via LDS, dwordx4.
// ---------------------------------------------------------------------------
__global__ __launch_bounds__(256, 6) void mfma_gemm_kernel(
    const bf16_t* __restrict__ A, const bf16_t* __restrict__ Bt,
    const float* __restrict__ bias, const bf16_t* __restrict__ Add, int addLd,
    bf16_t* __restrict__ C, int N, int K, int nT, int act)
{
  GEMM_SMEM
  int flat = blockIdx.x;
  int xcd = flat & 7, g = flat >> 3;
  int mT8 = (int)(gridDim.x / (unsigned)nT) >> 3;
  int mt = xcd*mT8 + g / nT;
  int nt = g % nT;
  int m0 = mt*128, n0 = nt*64;
  GEMM_PROLOG(A + (size_t)m0*K, Bt + (size_t)n0*K, K)
  GEMM_KLOOP(K)
  __syncthreads();
  #pragma unroll
  for (int ni = 0; ni < 2; ++ni) {
    int cl = wn*32 + ni*16 + fr;
    int gn = n0 + cl;
    float bv = bias[gn];
    #pragma unroll
    for (int mi = 0; mi < 4; ++mi) {
      #pragma unroll
      for (int r = 0; r < 4; ++r) {
        int ml = wm*64 + mi*16 + fq*4 + r;
        float val = acc[mi][ni][r] + bv;
        if (Add) val += bf2f(Add[(size_t)(m0+ml)*addLd + gn]);
        if (act == 1) val = siluf_(val);
        Cs[ml*72 + cl] = f2bf(val);
      }
    }
  }
  __syncthreads();
  int row = tid >> 1, c0 = (tid & 1)*32;
  #pragma unroll
  for (int q = 0; q < 4; ++q)
    *(uint4*)(C + (size_t)(m0+row)*N + n0 + c0 + q*8) =
        *(const uint4*)&Cs[row*72 + c0 + q*8];
}

// ---------------------------------------------------------------------------
// Wv GEMM variant: vt layout [blk=b*16+nchunk][kc=0..15][h=0..1023][e=0..7],
// k = kc*8+e (K=128 per chunk). Tile 128x64: rows gm = m0 + kk*16 + b with
// l = mt*8+kk -> nchunk = mt>>4, kc = mt&15, e = kk. Each thread writes
// 16B of 8 consecutive e at consecutive h -> 256B-contiguous segments.
// ---------------------------------------------------------------------------
__global__ __launch_bounds__(256, 6) void mfma_gemm_v_kernel(
    const bf16_t* __restrict__ A, const bf16_t* __restrict__ Bt,
    const float* __restrict__ bias, bf16_t* __restrict__ vt, int nT, int K)
{
  GEMM_SMEM
  int flat = blockIdx.x;
  int xcd = flat & 7, g = flat >> 3;
  int mT8 = (int)(gridDim.x / (unsigned)nT) >> 3;
  int mt = xcd*mT8 + g / nT;
  int nt = g % nT;
  int m0 = mt*128, n0 = nt*64;
  GEMM_PROLOG(A + (size_t)m0*K, Bt + (size_t)n0*K, K)
  GEMM_KLOOP(K)
  __syncthreads();
  #pragma unroll
  for (int ni = 0; ni < 2; ++ni) {
    int cl = wn*32 + ni*16 + fr;
    float bv = bias[n0 + cl];
    #pragma unroll
    for (int mi = 0; mi < 4; ++mi) {
      #pragma unroll
      for (int r = 0; r < 4; ++r) {
        int ml = wm*64 + mi*16 + fq*4 + r;
        Cs[ml*72 + cl] = f2bf(siluf_(acc[mi][ni][r] + bv));
      }
    }
  }
  __syncthreads();
  // thread: b = tid>>4, hl = (tid&15) + j*16 (j 0..3); writes 8 kk as 16B.
  {
    int b = tid >> 4;
    int nchunk = mt >> 4, kc = mt & 15;
    size_t ob = ((size_t)((b*NC + nchunk)*16 + kc))*8192;  // element base
    #pragma unroll
    for (int j = 0; j < 4; ++j) {
      int hl = (tid & 15) + j*16;
      uint4 s;
      s.x = (unsigned int)Cs[(0*16 + b)*72 + hl] |
            ((unsigned int)Cs[(1*16 + b)*72 + hl] << 16);
      s.y = (unsigned int)Cs[(2*16 + b)*72 + hl] |
            ((unsigned int)Cs[(3*16 + b)*72 + hl] << 16);
      s.z = (unsigned int)Cs[(4*16 + b)*72 + hl] |
            ((unsigned int)Cs[(5*16 + b)*72 + hl] << 16);
      s.w = (unsigned int)Cs[(6*16 + b)*72 + hl] |
            ((unsigned int)Cs[(7*16 + b)*72 + hl] << 16);
      *(uint4*)&vt[ob + (size_t)(n0 + hl)*8] = s;
    }
  }
}

// ---------------------------------------------------------------------------
// Attention scores via MFMA + softmax. TWO blocks per (b,n): blockIdx =
// blk*2 + half; each block computes 64 q-rows (q0 = half*64) against all
// 128 k-rows. LDS 52224 B (qs 64x136 + ks 128x136) -> 2 blocks/CU resident
// (vs 1 before), halved per-block serial softmax work.
// Writes fp32 probs to d_out AND bf16 probs (p_bf) for the PV GEMM.
// ---------------------------------------------------------------------------
__global__ __launch_bounds__(256) void attn_scores_mfma_kernel(
    const bf16_t* __restrict__ base, const float* __restrict__ qkg,
    const float* __restrict__ qkb, const float* __restrict__ rpb,
    float* __restrict__ attn_out, bf16_t* __restrict__ p_bf)
{
  __shared__ bf16_t qs[64*136];
  __shared__ bf16_t ks[128*136];
  int blk = blockIdx.x >> 1, half = blockIdx.x & 1;
  int b = blk >> 4, n = blk & 15;
  int tid = threadIdx.x;
  {
    int r = tid >> 1, z0 = (tid & 1)*64;
    size_t rowoff = ((size_t)((n*128 + r)*B_DIM + b))*BASE_N + 512 + z0;
    #pragma unroll
    for (int cchunk = 0; cchunk < 8; ++cchunk) {
      float t8[8], qv[8], kv[8];
      load8(base + rowoff + cchunk*8, t8);
      #pragma unroll
      for (int j = 0; j < 8; ++j) {
        int z = z0 + cchunk*8 + j;
        float zs = siluf_(t8[j]);
        qv[j] = fmaf(zs, qkg[z],     qkb[z]);
        kv[j] = fmaf(zs, qkg[128+z], qkb[128+z]);
      }
      store8bf(&ks[r*136 + z0 + cchunk*8], kv);
      if ((r >> 6) == half)
        store8bf(&qs[(r & 63)*136 + z0 + cchunk*8], qv);
    }
  }
  __syncthreads();
  int wave = tid >> 6, lane = tid & 63;
  int fr = lane & 15, fq = lane >> 4;
  f32x4 acc[8];
  #pragma unroll
  for (int j = 0; j < 8; ++j)
    acc[j] = (f32x4){0.f,0.f,0.f,0.f};
  #pragma unroll
  for (int kk = 0; kk < 4; ++kk) {
    short8 af, bfr[8];
    af = *(const short8*)&qs[(wave*16 + fr)*136 + kk*32 + fq*8];
    #pragma unroll
    for (int ni = 0; ni < 8; ++ni)
      bfr[ni] = *(const short8*)&ks[(ni*16 + fr)*136 + kk*32 + fq*8];
    #pragma unroll
    for (int ni = 0; ni < 8; ++ni)
      acc[ni] = __builtin_amdgcn_mfma_f32_16x16x32_bf16(
          af, bfr[ni], acc[ni], 0, 0, 0);
  }
  const float scale = 0.08838834764831845f;  // 1/sqrt(128)
  float mrow[4], srow[4];
  #pragma unroll
  for (int r = 0; r < 4; ++r) mrow[r] = -1e30f;
  #pragma unroll
  for (int ni = 0; ni < 8; ++ni)
    #pragma unroll
    for (int r = 0; r < 4; ++r) {
      int ig = half*64 + wave*16 + fq*4 + r;
      int j = ni*16 + fr;
      float v = fmaf(acc[ni][r], scale, rpb[1023 + j - ig]);
      acc[ni][r] = v;
      mrow[r] = fmaxf(mrow[r], v);
    }
  #pragma unroll
  for (int r = 0; r < 4; ++r) {
    float m = mrow[r];
    m = fmaxf(m, __shfl_xor(m, 1));
    m = fmaxf(m, __shfl_xor(m, 2));
    m = fmaxf(m, __shfl_xor(m, 4));
    m = fmaxf(m, __shfl_xor(m, 8));
    mrow[r] = m;
    srow[r] = 0.f;
  }
  #pragma unroll
  for (int ni = 0; ni < 8; ++ni)
    #pragma unroll
    for (int r = 0; r < 4; ++r) {
      float e = __expf(acc[ni][r] - mrow[r]);
      acc[ni][r] = e;
      srow[r] += e;
    }
  #pragma unroll
  for (int r = 0; r < 4; ++r) {
    float s = srow[r];
    s += __shfl_xor(s, 1);
    s += __shfl_xor(s, 2);
    s += __shfl_xor(s, 4);
    s += __shfl_xor(s, 8);
    srow[r] = 1.f/s;
  }
  #pragma unroll
  for (int r = 0; r < 4; ++r) {
    int ig = half*64 + wave*16 + fq*4 + r;
    size_t o = ((size_t)blk*128 + ig)*128;
    #pragma unroll
    for (int ni = 0; ni < 8; ++ni) {
      float val = acc[ni][r]*srow[r];
      attn_out[o + ni*16 + fr] = val;
      p_bf[o + ni*16 + fr] = f2bf(val);
    }
  }
}

// ---------------------------------------------------------------------------
// hr = (P @ V) * silu(r) via MFMA. Grid flat: blk*16 + htile (64-wide).
// Custom B staging for the [blk][kc][h][8] vt layout: global chunk c of row h
// lives at blk*131072 + c*8192 + h*8; same glds16 slot/swizzle scheme as the
// GEMM core (slot relation (c + (row&7))&7 preserved on store and read).
// ---------------------------------------------------------------------------
__global__ __launch_bounds__(256, 6) void attn_pv_kernel(
    const bf16_t* __restrict__ p_bf, const bf16_t* __restrict__ vt,
    const bf16_t* __restrict__ base, bf16_t* __restrict__ hr)
{
  GEMM_SMEM
  int blk = blockIdx.x >> 4, ht = blockIdx.x & 15;
  int b = blk >> 4, n = blk & 15;
  const int K = 128;
  int tid = threadIdx.x;
  int wave = tid >> 6, lane = tid & 63;
  int lrow = lane >> 3, lchunk = ((lane & 7) - lrow) & 7;
  const bf16_t* Ag = p_bf + (size_t)blk*16384
                     + (size_t)(wave*32 + lrow)*K + lchunk*8;
  const bf16_t* Bg = vt + (size_t)blk*131072 + (size_t)lchunk*8192
                     + (size_t)(ht*64 + wave*16 + lrow)*8;
  int wm = wave >> 1, wn = wave & 1;
  int fr = lane & 15, fq = lane >> 4;
  f32x4 acc[4][2];
  #pragma unroll
  for (int i = 0; i < 4; ++i)
    #pragma unroll
    for (int j = 0; j < 2; ++j)
      acc[i][j] = (f32x4){0.f,0.f,0.f,0.f};
  for (int k0 = 0; k0 < K; k0 += 64) {
    __syncthreads();
    #pragma unroll
    for (int j = 0; j < 4; ++j)
      glds16(Ag + (size_t)j*8*K + k0, As + (wave*32 + j*8)*64);
    #pragma unroll
    for (int j = 0; j < 2; ++j)
      glds16(Bg + (size_t)(k0 >> 3)*8192 + j*64, Bs + (wave*16 + j*8)*64);
    __syncthreads();
    #pragma unroll
    for (int kk = 0; kk < 2; ++kk) {
      short8 af[4], bfr[2];
      #pragma unroll
      for (int mi = 0; mi < 4; ++mi) {
        int R = wm*64 + mi*16 + fr;
        af[mi] = *(const short8*)&As[R*64 + (((kk<<2)+fq+R)&7)*8];
      }
      #pragma unroll
      for (int ni = 0; ni < 2; ++ni) {
        int R = wn*32 + ni*16 + fr;
        bfr[ni] = *(const short8*)&Bs[R*64 + (((kk<<2)+fq+R)&7)*8];
      }
      #pragma unroll
      for (int mi = 0; mi < 4; ++mi)
        #pragma unroll
        for (int ni = 0; ni < 2; ++ni)
          acc[mi][ni] = __builtin_amdgcn_mfma_f32_16x16x32_bf16(
              af[mi], bfr[ni], acc[mi][ni], 0, 0, 0);
    }
  }
  __syncthreads();
  #pragma unroll
  for (int ni = 0; ni < 2; ++ni) {
    int cl = wn*32 + ni*16 + fr;
    int hg = ht*64 + cl;
    #pragma unroll
    for (int mi = 0; mi < 4; ++mi) {
      #pragma unroll
      for (int r = 0; r < 4; ++r) {
        int ml = wm*64 + mi*16 + fq*4 + r;
        size_t rowg = (size_t)((n*128 + ml)*B_DIM + b);
        float rg = bf2f(base[rowg*BASE_N + 640 + hg]);
        Cs[ml*72 + cl] = f2bf(acc[mi][ni][r]*siluf_(rg));
      }
    }
  }
  __syncthreads();
  int row = tid >> 1, c0 = (tid & 1)*32;
  size_t rowg = (size_t)((n*128 + row)*B_DIM + b);
  #pragma unroll
  for (int q = 0; q < 4; ++q)
    *(uint4*)(hr + rowg*H_DIM + ht*64 + c0 + q*8) =
        *(const uint4*)&Cs[row*72 + c0 + q*8];
}

// ---------------------------------------------------------------------------
// out = residual + u*(h2 - residual), then RMSNorm * norm_scalar.
// 256 threads = 4 rows per block (one wave per row).
// ---------------------------------------------------------------------------
__global__ __launch_bounds__(256) void final_kernel(
    const float* __restrict__ x, const bf16_t* __restrict__ h2,
    const bf16_t* __restrict__ base, const float* __restrict__ ns,
    float* __restrict__ out)
{
  int row = blockIdx.x*4 + (threadIdx.x >> 6);
  int t = threadIdx.x & 63;
  size_t ro = (size_t)row*D_DIM + t*8;
  float xv[8]; load8(x + ro, xv);
  float hv[8]; load8(h2 + ro, hv);
  float uv[8]; load8(base + (size_t)row*BASE_N + t*8, uv);
  float o[8];
  float ss = 0.f;
  #pragma unroll
  for (int i = 0; i < 8; ++i) {
    float u = sigmoidf_(uv[i]);
    o[i] = xv[i] + u*(hv[i] - xv[i]);
    ss += o[i]*o[i];
  }
  #pragma unroll
  for (int m = 1; m < 64; m <<= 1) ss += __shfl_xor(ss, m);
  float inv = rsqrtf(ss*(1.f/(float)D_DIM) + 1e-6f) * ns[0];
  float4 r0, r1;
  r0.x = o[0]*inv; r0.y = o[1]*inv; r0.z = o[2]*inv; r0.w = o[3]*inv;
  r1.x = o[4]*inv; r1.y = o[5]*inv; r1.z = o[6]*inv; r1.w = o[7]*inv;
  *(float4*)(out + ro) = r0;
  *(float4*)(out + ro + 4) = r1;
}

// ---------------------------------------------------------------------------
extern "C" void kernel_launch(void* const* d_in, const int* in_sizes, int n_in,
                              void* d_out, int out_size, void* d_ws, size_t ws_size,
                              hipStream_t stream)
{
  const float* x     = (const float*)d_in[0];
  const float* delta = (const float*)d_in[1];
  const float* alpha = (const float*)d_in[2];
  const float* beta  = (const float*)d_in[3];
  const float* gamma = (const float*)d_in[4];
  const float* omega = (const float*)d_in[5];
  const float* Wv    = (const float*)d_in[6];
  const float* bv    = (const float*)d_in[7];
  const float* Wmx   = (const float*)d_in[8];
  const float* bmx   = (const float*)d_in[9];
  const float* Wh    = (const float*)d_in[10];
  const float* bh    = (const float*)d_in[11];
  const float* qkg   = (const float*)d_in[12];
  const float* qkb   = (const float*)d_in[13];
  const float* rpb   = (const float*)d_in[14];
  const float* ns    = (const float*)d_in[15];

  float* out  = (float*)d_out;
  float* attn = out + (size_t)ROWS*D_DIM;

  char* outb = (char*)d_out;
  bf16_t* x_bf  = (bf16_t*)outb;            // dead after Wv GEMM
  bf16_t* p_bf  = (bf16_t*)outb;            // written by scores, read by PV
  bf16_t* Wv_t  = (bf16_t*)(outb + 33554432ull);
  bf16_t* Wmx_t = (bf16_t*)(outb + 34603008ull);
  bf16_t* Wh_t  = (bf16_t*)(outb + 36831232ull);

  const size_t WS_NEED = 310378496ull;
  if (ws_size < WS_NEED) return;
  char* wsb = (char*)d_ws;
  bf16_t* mx_bf   = (bf16_t*)(wsb);
  bf16_t* vt      = (bf16_t*)(wsb + 33554432ull);
  bf16_t* base_bf = (bf16_t*)(wsb + 100663296ull);
  bf16_t* hr_bf   = (bf16_t*)(wsb + 243269632ull);
  float*  carry   = (float*)(wsb + 100663296ull);
  bf16_t* h2_bf   = mx_bf;

  // weight transposes (one launch)
  transpose_all_kernel<<<2112, 256, 0, stream>>>(Wv, Wmx, Wh, Wv_t, Wmx_t, Wh_t);
  // EMA segmented scan (also produces x_bf)
  ema_carry_kernel<<<1024, 256, 0, stream>>>(x, delta, alpha, x_bf, carry);
  ema_combine_kernel<<<32, 256, 0, stream>>>(delta, alpha, carry);
  ema_apply_kernel<<<1024, 256, 0, stream>>>(x_bf, delta, alpha, beta, gamma,
                                             omega, carry, mx_bf);
  // vt = silu(x @ Wv + bv), [blk][kc][h][8] layout (N=1024 -> 16 tiles of 64)
  mfma_gemm_v_kernel<<<4096, 256, 0, stream>>>(x_bf, Wv_t, bv, vt, 16, D_DIM);
  // base = mx @ Wmx + bmx (N=2176 -> 34 tiles of 64)
  mfma_gemm_kernel<<<8704, 256, 0, stream>>>(
      mx_bf, Wmx_t, bmx, nullptr, 0, base_bf, BASE_N, D_DIM, 34, 0);
  // attn probs (fp32 -> d_out, bf16 -> p_bf); 2 q-half blocks per (b,n)
  attn_scores_mfma_kernel<<<B_DIM*NC*2, 256, 0, stream>>>(
      base_bf, qkg, qkb, rpb, attn, p_bf);
  // hr = (P @ V) * silu(r)  (16 h-tiles of 64)
  attn_pv_kernel<<<4096, 256, 0, stream>>>(p_bf, vt, base_bf, hr_bf);
  // h2 = silu(hx + hr @ Wh + bh) (N=512 -> 8 tiles of 64)
  mfma_gemm_kernel<<<2048, 256, 0, stream>>>(
      hr_bf, Wh_t, bh, base_bf + 1664, BASE_N, h2_bf, D_DIM, H_DIM, 8, 1);
  // gated residual + RMSNorm
  final_kernel<<<ROWS/4, 256, 0, stream>>>(x, h2_bf, base_bf, ns, out);
}

// Round 11
// 556.608 us; speedup vs baseline: 1.1427x; 1.0331x over previous
//
#include <hip/hip_runtime.h>
#include <math.h>

// Problem dims
#define L_DIM 2048
#define B_DIM 16
#define D_DIM 512
#define H_DIM 1024
#define Z_DIM 128
#define NC    16
#define BASE_N 2176            // Z + H + 2D
#define ROWS  (L_DIM*B_DIM)    // 32768
#define NSEG  32
#define SLEN  64
#define CHAINS 8192            // B*D

typedef unsigned short bf16_t;
typedef __attribute__((ext_vector_type(8))) short short8;
typedef __attribute__((ext_vector_type(4))) float f32x4;

__device__ __forceinline__ float sigmoidf_(float x){ return 1.f/(1.f+__expf(-x)); }
__device__ __forceinline__ float siluf_(float x){ return x/(1.f+__expf(-x)); }
__device__ __forceinline__ float fbits(unsigned int b){ union{unsigned int i; float f;} c; c.i=b; return c.f; }
__device__ __forceinline__ unsigned short f2bf(float f){
  union{float f; unsigned int i;} c; c.f=f;
  unsigned int r = c.i + 0x7FFFu + ((c.i>>16)&1u);   // RNE
  return (unsigned short)(r>>16);
}
__device__ __forceinline__ float bf2f(unsigned short u){ return fbits(((unsigned int)u)<<16); }

__device__ __forceinline__ void load8(const float* __restrict__ p, float* d){
  float4 a = *(const float4*)p; float4 b = *(const float4*)(p+4);
  d[0]=a.x; d[1]=a.y; d[2]=a.z; d[3]=a.w; d[4]=b.x; d[5]=b.y; d[6]=b.z; d[7]=b.w;
}
__device__ __forceinline__ void load8(const bf16_t* __restrict__ p, float* d){
  uint4 u = *(const uint4*)p;
  d[0]=fbits(u.x<<16); d[1]=fbits(u.x&0xFFFF0000u);
  d[2]=fbits(u.y<<16); d[3]=fbits(u.y&0xFFFF0000u);
  d[4]=fbits(u.z<<16); d[5]=fbits(u.z&0xFFFF0000u);
  d[6]=fbits(u.w<<16); d[7]=fbits(u.w&0xFFFF0000u);
}
__device__ __forceinline__ void store8bf(bf16_t* p, const float* v){
  uint4 s;
  s.x = (unsigned int)f2bf(v[0]) | ((unsigned int)f2bf(v[1])<<16);
  s.y = (unsigned int)f2bf(v[2]) | ((unsigned int)f2bf(v[3])<<16);
  s.z = (unsigned int)f2bf(v[4]) | ((unsigned int)f2bf(v[5])<<16);
  s.w = (unsigned int)f2bf(v[6]) | ((unsigned int)f2bf(v[7])<<16);
  *(uint4*)p = s;
}

// async global(16B/lane) -> LDS, wave-uniform LDS base + lane*16
__device__ __forceinline__ void glds16(const void* g, void* l) {
  __builtin_amdgcn_global_load_lds(
      (const __attribute__((address_space(1))) unsigned int*)g,
      (__attribute__((address_space(3))) unsigned int*)l, 16, 0, 0);
}

// ---------------------------------------------------------------------------
// MERGED pre-kernel: blocks [0,1024) = EMA carry; [1024,3136) = weight
// transposes. Independent work co-scheduled to hide the transpose under the
// carry scan and drop one launch gap.
// ---------------------------------------------------------------------------
__global__ __launch_bounds__(256) void pre_kernel(
    const float* __restrict__ x, const float* __restrict__ delta,
    const float* __restrict__ alpha, bf16_t* __restrict__ xb,
    float* __restrict__ carry,
    const float* __restrict__ Wv, const float* __restrict__ Wmx,
    const float* __restrict__ Wh, bf16_t* __restrict__ Wvt,
    bf16_t* __restrict__ Wmxt, bf16_t* __restrict__ Wht)
{
  __shared__ float t[32][33];
  if (blockIdx.x < 1024) {
    // ---- EMA segmented scan carry; bwd scan from registers ----
    int idx = blockIdx.x*256 + threadIdx.x;      // 0..262143
    int d = idx & 511, c = idx & 8191, s = idx >> 13;   // s in 0..31
    float qf0 = 1.f - sigmoidf_(delta[d*2+0])*sigmoidf_(alpha[d*2+0]);
    float qf1 = 1.f - sigmoidf_(delta[d*2+1])*sigmoidf_(alpha[d*2+1]);
    int dd = d + 512;
    float qb0 = 1.f - sigmoidf_(delta[dd*2+0])*sigmoidf_(alpha[dd*2+0]);
    float qb1 = 1.f - sigmoidf_(delta[dd*2+1])*sigmoidf_(alpha[dd*2+1]);
    size_t off = (size_t)s*SLEN*CHAINS + c;
    float xr[SLEN];
    float h0=0.f, h1=0.f;
    #pragma unroll
    for (int tt = 0; tt < SLEN; ++tt) {
      size_t a = off + (size_t)tt*CHAINS;
      float xv = x[a];
      unsigned short xv16 = f2bf(xv);
      xb[a] = xv16;
      xr[tt] = bf2f(xv16);
      h0 = fmaf(qf0, h0, xv); h1 = fmaf(qf1, h1, xv);
    }
    float g0=0.f, g1=0.f;
    #pragma unroll
    for (int tt = SLEN-1; tt >= 0; --tt) {
      float xv = xr[tt];
      g0 = fmaf(qb0, g0, xv); g1 = fmaf(qb1, g1, xv);
    }
    carry[(size_t)s*CHAINS + c]              = h0;
    carry[(size_t)s*CHAINS + c + 262144]     = h1;
    carry[(size_t)s*CHAINS + c + 524288]     = g0;
    carry[(size_t)s*CHAINS + c + 786432]     = g1;
  } else {
    // ---- weight transposes: W (K x N fp32) -> Wt (N x K bf16) ----
    int blk = blockIdx.x - 1024;
    const float* W; bf16_t* Wt; int K, N, bx, by;
    if (blk < 512)       { W=Wv;  Wt=Wvt;  K=512;  N=1024; bx=blk&31;  by=blk>>5; }
    else if (blk < 1600) { blk-=512;  W=Wmx; Wt=Wmxt; K=512;  N=2176; bx=blk%68; by=blk/68; }
    else                 { blk-=1600; W=Wh;  Wt=Wht;  K=1024; N=512;  bx=blk&15; by=blk>>4; }
    int lx = threadIdx.x & 31, ly = threadIdx.x >> 5;
    #pragma unroll
    for (int i = 0; i < 32; i += 8)
      t[ly+i][lx] = W[(size_t)(by*32+ly+i)*N + bx*32 + lx];
    __syncthreads();
    #pragma unroll
    for (int i = 0; i < 32; i += 8)
      Wt[(size_t)(bx*32+ly+i)*K + by*32 + lx] = f2bf(t[lx][ly+i]);
  }
}

__global__ __launch_bounds__(256) void ema_combine_kernel(
    const float* __restrict__ delta, const float* __restrict__ alpha,
    float* __restrict__ carry)
{
  int c = blockIdx.x*256 + threadIdx.x;   // 0..8191
  int d = c & 511;
  float qf0 = 1.f - sigmoidf_(delta[d*2+0])*sigmoidf_(alpha[d*2+0]);
  float qf1 = 1.f - sigmoidf_(delta[d*2+1])*sigmoidf_(alpha[d*2+1]);
  int dd = d + 512;
  float qb0 = 1.f - sigmoidf_(delta[dd*2+0])*sigmoidf_(alpha[dd*2+0]);
  float qb1 = 1.f - sigmoidf_(delta[dd*2+1])*sigmoidf_(alpha[dd*2+1]);
  float df0=qf0, df1=qf1, db0=qb0, db1=qb1;
  #pragma unroll
  for (int i = 0; i < 6; ++i) { df0*=df0; df1*=df1; db0*=db0; db1*=db1; }  // q^64
  float h0=0.f, h1=0.f;
  for (int s = 0; s < NSEG; ++s) {
    size_t a = (size_t)s*CHAINS + c;
    float t0 = carry[a], t1 = carry[a+262144];
    carry[a] = h0; carry[a+262144] = h1;
    h0 = fmaf(df0, h0, t0); h1 = fmaf(df1, h1, t1);
  }
  float g0=0.f, g1=0.f;
  for (int s = NSEG-1; s >= 0; --s) {
    size_t a = (size_t)s*CHAINS + c;
    float t0 = carry[a+524288], t1 = carry[a+786432];
    carry[a+524288] = g0; carry[a+786432] = g1;
    g0 = fmaf(db0, g0, t0); g1 = fmaf(db1, g1, t1);
  }
}

__global__ __launch_bounds__(256) void ema_apply_kernel(
    const bf16_t* __restrict__ xb, const float* __restrict__ delta,
    const float* __restrict__ alpha, const float* __restrict__ beta,
    const float* __restrict__ gamma, const float* __restrict__ omega,
    const float* __restrict__ carry, bf16_t* __restrict__ mx)
{
  int idx = blockIdx.x*256 + threadIdx.x;
  int d = idx & 511, c = idx & 8191, s = idx >> 13;
  const float rs = 0.70710678118654752f;
  float pf0 = sigmoidf_(delta[d*2+0]), pf1 = sigmoidf_(delta[d*2+1]);
  float qf0 = 1.f - pf0*sigmoidf_(alpha[d*2+0]);
  float qf1 = 1.f - pf1*sigmoidf_(alpha[d*2+1]);
  float cf0 = pf0*beta[d*2+0]*gamma[d*2+0]*rs;
  float cf1 = pf1*beta[d*2+1]*gamma[d*2+1]*rs;
  int dd = d + 512;
  float pb0 = sigmoidf_(delta[dd*2+0]), pb1 = sigmoidf_(delta[dd*2+1]);
  float qb0 = 1.f - pb0*sigmoidf_(alpha[dd*2+0]);
  float qb1 = 1.f - pb1*sigmoidf_(alpha[dd*2+1]);
  float cb0 = pb0*beta[dd*2+0]*gamma[dd*2+0]*rs;
  float cb1 = pb1*beta[dd*2+1]*gamma[dd*2+1]*rs;
  float om = omega[d];
  size_t off = (size_t)s*SLEN*CHAINS + c;
  float h0 = carry[(size_t)s*CHAINS + c];
  float h1 = carry[(size_t)s*CHAINS + c + 262144];
  float yv[SLEN];
  #pragma unroll
  for (int t = 0; t < SLEN; ++t) {
    float xv = bf2f(xb[off + (size_t)t*CHAINS]);
    h0 = fmaf(qf0, h0, xv); h1 = fmaf(qf1, h1, xv);
    yv[t] = fmaf(cf0, h0, cf1*h1);
  }
  float g0 = carry[(size_t)s*CHAINS + c + 524288];
  float g1 = carry[(size_t)s*CHAINS + c + 786432];
  #pragma unroll
  for (int t = SLEN-1; t >= 0; --t) {
    size_t a = off + (size_t)t*CHAINS;
    float xv = bf2f(xb[a]);
    g0 = fmaf(qb0, g0, xv); g1 = fmaf(qb1, g1, xv);
    float sv = yv[t] + fmaf(cb0, g0, cb1*g1) + xv*om;
    mx[a] = f2bf(siluf_(sv));
  }
}

// ===========================================================================
// Shared MFMA GEMM core (round-7 verified): BM=128 x BN=64 tile, acc[4][2],
// single-buffer BK=64, XOR-swizzled LDS. Now a __device__ core taking the
// block id and logical grid size explicitly so independent GEMMs can be
// packed into one launch (tail-fill). smem = 24576 B shared buffer.
// ===========================================================================
#define GEMM_PROLOG(Aptr, Bptr, Kdim)                                        \
  int tid = threadIdx.x;                                                     \
  int wave = tid >> 6, lane = tid & 63;                                      \
  int lrow = lane >> 3, lchunk = ((lane & 7) - lrow) & 7;                    \
  const bf16_t* Ag = (Aptr) + (size_t)(wave*32 + lrow)*(Kdim) + lchunk*8;    \
  const bf16_t* Bg = (Bptr) + (size_t)(wave*16 + lrow)*(Kdim) + lchunk*8;    \
  int wm = wave >> 1, wn = wave & 1;                                         \
  int fr = lane & 15, fq = lane >> 4;                                        \
  f32x4 acc[4][2];                                                           \
  _Pragma("unroll") for (int i = 0; i < 4; ++i)                              \
    _Pragma("unroll") for (int j = 0; j < 2; ++j)                            \
      acc[i][j] = (f32x4){0.f,0.f,0.f,0.f};

#define GEMM_KLOOP(Kdim)                                                     \
  for (int k0 = 0; k0 < (Kdim); k0 += 64) {                                  \
    __syncthreads();                                                         \
    _Pragma("unroll") for (int j = 0; j < 4; ++j)                            \
      glds16(Ag + (size_t)j*8*(Kdim) + k0, As + (wave*32 + j*8)*64);         \
    _Pragma("unroll") for (int j = 0; j < 2; ++j)                            \
      glds16(Bg + (size_t)j*8*(Kdim) + k0, Bs + (wave*16 + j*8)*64);         \
    __syncthreads();                                                         \
    _Pragma("unroll") for (int kk = 0; kk < 2; ++kk) {                       \
      short8 af[4], bfr[2];                                                  \
      _Pragma("unroll") for (int mi = 0; mi < 4; ++mi) {                     \
        int R = wm*64 + mi*16 + fr;                                          \
        af[mi] = *(const short8*)&As[R*64 + (((kk<<2)+fq+R)&7)*8];           \
      }                                                                      \
      _Pragma("unroll") for (int ni = 0; ni < 2; ++ni) {                     \
        int R = wn*32 + ni*16 + fr;                                          \
        bfr[ni] = *(const short8*)&Bs[R*64 + (((kk<<2)+fq+R)&7)*8];          \
      }                                                                      \
      _Pragma("unroll") for (int mi = 0; mi < 4; ++mi)                       \
        _Pragma("unroll") for (int ni = 0; ni < 2; ++ni)                     \
          acc[mi][ni] = __builtin_amdgcn_mfma_f32_16x16x32_bf16(             \
              af[mi], bfr[ni], acc[mi][ni], 0, 0, 0);                        \
    }                                                                        \
  }

// Generic GEMM core: C(bf16, MxN) = act(A @ Bt^T + bias [+ Add])
__device__ __forceinline__ void gemm_core(
    char* smem, int flat, int nGrid,
    const bf16_t* __restrict__ A, const bf16_t* __restrict__ Bt,
    const float* __restrict__ bias, const bf16_t* __restrict__ Add, int addLd,
    bf16_t* __restrict__ C, int N, int K, int nT, int act)
{
  bf16_t* As = (bf16_t*)smem;            // 128x64
  bf16_t* Bs = (bf16_t*)(smem + 16384);  // 64x64
  bf16_t* Cs = (bf16_t*)smem;            // 128x72, reused after K-loop
  int xcd = flat & 7, g = flat >> 3;
  int mT8 = (nGrid / nT) >> 3;
  int mt = xcd*mT8 + g / nT;
  int nt = g % nT;
  int m0 = mt*128, n0 = nt*64;
  GEMM_PROLOG(A + (size_t)m0*K, Bt + (size_t)n0*K, K)
  GEMM_KLOOP(K)
  __syncthreads();
  #pragma unroll
  for (int ni = 0; ni < 2; ++ni) {
    int cl = wn*32 + ni*16 + fr;
    int gn = n0 + cl;
    float bv = bias[gn];
    #pragma unroll
    for (int mi = 0; mi < 4; ++mi) {
      #pragma unroll
      for (int r = 0; r < 4; ++r) {
        int ml = wm*64 + mi*16 + fq*4 + r;
        float val = acc[mi][ni][r] + bv;
        if (Add) val += bf2f(Add[(size_t)(m0+ml)*addLd + gn]);
        if (act == 1) val = siluf_(val);
        Cs[ml*72 + cl] = f2bf(val);
      }
    }
  }
  __syncthreads();
  int row = tid >> 1, c0 = (tid & 1)*32;
  #pragma unroll
  for (int q = 0; q < 4; ++q)
    *(uint4*)(C + (size_t)(m0+row)*N + n0 + c0 + q*8) =
        *(const uint4*)&Cs[row*72 + c0 + q*8];
}

// Wv GEMM core: vt layout [blk=b*16+nchunk][kc=0..15][h=0..1023][e=0..7].
__device__ __forceinline__ void gemm_v_core(
    char* smem, int flat, int nGrid,
    const bf16_t* __restrict__ A, const bf16_t* __restrict__ Bt,
    const float* __restrict__ bias, bf16_t* __restrict__ vt, int nT, int K)
{
  bf16_t* As = (bf16_t*)smem;
  bf16_t* Bs = (bf16_t*)(smem + 16384);
  bf16_t* Cs = (bf16_t*)smem;
  int xcd = flat & 7, g = flat >> 3;
  int mT8 = (nGrid / nT) >> 3;
  int mt = xcd*mT8 + g / nT;
  int nt = g % nT;
  int m0 = mt*128, n0 = nt*64;
  GEMM_PROLOG(A + (size_t)m0*K, Bt + (size_t)n0*K, K)
  GEMM_KLOOP(K)
  __syncthreads();
  #pragma unroll
  for (int ni = 0; ni < 2; ++ni) {
    int cl = wn*32 + ni*16 + fr;
    float bv = bias[n0 + cl];
    #pragma unroll
    for (int mi = 0; mi < 4; ++mi) {
      #pragma unroll
      for (int r = 0; r < 4; ++r) {
        int ml = wm*64 + mi*16 + fq*4 + r;
        Cs[ml*72 + cl] = f2bf(siluf_(acc[mi][ni][r] + bv));
      }
    }
  }
  __syncthreads();
  // thread: b = tid>>4, hl = (tid&15) + j*16 (j 0..3); writes 8 kk as 16B.
  {
    int b = tid >> 4;
    int nchunk = mt >> 4, kc = mt & 15;
    size_t ob = ((size_t)((b*NC + nchunk)*16 + kc))*8192;  // element base
    #pragma unroll
    for (int j = 0; j < 4; ++j) {
      int hl = (tid & 15) + j*16;
      uint4 s;
      s.x = (unsigned int)Cs[(0*16 + b)*72 + hl] |
            ((unsigned int)Cs[(1*16 + b)*72 + hl] << 16);
      s.y = (unsigned int)Cs[(2*16 + b)*72 + hl] |
            ((unsigned int)Cs[(3*16 + b)*72 + hl] << 16);
      s.z = (unsigned int)Cs[(4*16 + b)*72 + hl] |
            ((unsigned int)Cs[(5*16 + b)*72 + hl] << 16);
      s.w = (unsigned int)Cs[(6*16 + b)*72 + hl] |
            ((unsigned int)Cs[(7*16 + b)*72 + hl] << 16);
      *(uint4*)&vt[ob + (size_t)(n0 + hl)*8] = s;
    }
  }
}

// ---------------------------------------------------------------------------
// MERGED GEMM launch: blocks [0,8704) = Wmx GEMM (base = mx @ Wmx + bmx);
// [8704,12800) = Wv GEMM (vt). Independent; packed to fill dispatch tails.
// Offset 8704 is a multiple of 8 so the XCD swizzle (flat&7) is preserved.
// ---------------------------------------------------------------------------
__global__ __launch_bounds__(256, 6) void gemm_wmx_v_kernel(
    const bf16_t* __restrict__ mx, const bf16_t* __restrict__ Wmxt,
    const float* __restrict__ bmx, bf16_t* __restrict__ baseo,
    const bf16_t* __restrict__ xbf, const bf16_t* __restrict__ Wvt,
    const float* __restrict__ bv, bf16_t* __restrict__ vt)
{
  __shared__ __align__(16) char smem[24576];
  int blk = blockIdx.x;
  if (blk < 8704)
    gemm_core(smem, blk, 8704, mx, Wmxt, bmx, nullptr, 0,
              baseo, BASE_N, D_DIM, 34, 0);
  else
    gemm_v_core(smem, blk - 8704, 4096, xbf, Wvt, bv, vt, 16, D_DIM);
}

// Standalone generic GEMM (used for Wh).
__global__ __launch_bounds__(256, 6) void mfma_gemm_kernel(
    const bf16_t* __restrict__ A, const bf16_t* __restrict__ Bt,
    const float* __restrict__ bias, const bf16_t* __restrict__ Add, int addLd,
    bf16_t* __restrict__ C, int N, int K, int nT, int act)
{
  __shared__ __align__(16) char smem[24576];
  gemm_core(smem, blockIdx.x, (int)gridDim.x, A, Bt, bias, Add, addLd,
            C, N, K, nT, act);
}

// ---------------------------------------------------------------------------
// Attention scores via MFMA + softmax. TWO blocks per (b,n): blockIdx =
// blk*2 + half; each block computes 64 q-rows (q0 = half*64) against all
// 128 k-rows. LDS 52224 B (qs 64x136 + ks 128x136) -> 2 blocks/CU resident.
// Writes fp32 probs to d_out AND bf16 probs (p_bf) for the PV GEMM.
// ---------------------------------------------------------------------------
__global__ __launch_bounds__(256) void attn_scores_mfma_kernel(
    const bf16_t* __restrict__ base, const float* __restrict__ qkg,
    const float* __restrict__ qkb, const float* __restrict__ rpb,
    float* __restrict__ attn_out, bf16_t* __restrict__ p_bf)
{
  __shared__ bf16_t qs[64*136];
  __shared__ bf16_t ks[128*136];
  int blk = blockIdx.x >> 1, half = blockIdx.x & 1;
  int b = blk >> 4, n = blk & 15;
  int tid = threadIdx.x;
  {
    int r = tid >> 1, z0 = (tid & 1)*64;
    size_t rowoff = ((size_t)((n*128 + r)*B_DIM + b))*BASE_N + 512 + z0;
    #pragma unroll
    for (int cchunk = 0; cchunk < 8; ++cchunk) {
      float t8[8], qv[8], kv[8];
      load8(base + rowoff + cchunk*8, t8);
      #pragma unroll
      for (int j = 0; j < 8; ++j) {
        int z = z0 + cchunk*8 + j;
        float zs = siluf_(t8[j]);
        qv[j] = fmaf(zs, qkg[z],     qkb[z]);
        kv[j] = fmaf(zs, qkg[128+z], qkb[128+z]);
      }
      store8bf(&ks[r*136 + z0 + cchunk*8], kv);
      if ((r >> 6) == half)
        store8bf(&qs[(r & 63)*136 + z0 + cchunk*8], qv);
    }
  }
  __syncthreads();
  int wave = tid >> 6, lane = tid & 63;
  int fr = lane & 15, fq = lane >> 4;
  f32x4 acc[8];
  #pragma unroll
  for (int j = 0; j < 8; ++j)
    acc[j] = (f32x4){0.f,0.f,0.f,0.f};
  #pragma unroll
  for (int kk = 0; kk < 4; ++kk) {
    short8 af, bfr[8];
    af = *(const short8*)&qs[(wave*16 + fr)*136 + kk*32 + fq*8];
    #pragma unroll
    for (int ni = 0; ni < 8; ++ni)
      bfr[ni] = *(const short8*)&ks[(ni*16 + fr)*136 + kk*32 + fq*8];
    #pragma unroll
    for (int ni = 0; ni < 8; ++ni)
      acc[ni] = __builtin_amdgcn_mfma_f32_16x16x32_bf16(
          af, bfr[ni], acc[ni], 0, 0, 0);
  }
  const float scale = 0.08838834764831845f;  // 1/sqrt(128)
  float mrow[4], srow[4];
  #pragma unroll
  for (int r = 0; r < 4; ++r) mrow[r] = -1e30f;
  #pragma unroll
  for (int ni = 0; ni < 8; ++ni)
    #pragma unroll
    for (int r = 0; r < 4; ++r) {
      int ig = half*64 + wave*16 + fq*4 + r;
      int j = ni*16 + fr;
      float v = fmaf(acc[ni][r], scale, rpb[1023 + j - ig]);
      acc[ni][r] = v;
      mrow[r] = fmaxf(mrow[r], v);
    }
  #pragma unroll
  for (int r = 0; r < 4; ++r) {
    float m = mrow[r];
    m = fmaxf(m, __shfl_xor(m, 1));
    m = fmaxf(m, __shfl_xor(m, 2));
    m = fmaxf(m, __shfl_xor(m, 4));
    m = fmaxf(m, __shfl_xor(m, 8));
    mrow[r] = m;
    srow[r] = 0.f;
  }
  #pragma unroll
  for (int ni = 0; ni < 8; ++ni)
    #pragma unroll
    for (int r = 0; r < 4; ++r) {
      float e = __expf(acc[ni][r] - mrow[r]);
      acc[ni][r] = e;
      srow[r] += e;
    }
  #pragma unroll
  for (int r = 0; r < 4; ++r) {
    float s = srow[r];
    s += __shfl_xor(s, 1);
    s += __shfl_xor(s, 2);
    s += __shfl_xor(s, 4);
    s += __shfl_xor(s, 8);
    srow[r] = 1.f/s;
  }
  #pragma unroll
  for (int r = 0; r < 4; ++r) {
    int ig = half*64 + wave*16 + fq*4 + r;
    size_t o = ((size_t)blk*128 + ig)*128;
    #pragma unroll
    for (int ni = 0; ni < 8; ++ni) {
      float val = acc[ni][r]*srow[r];
      attn_out[o + ni*16 + fr] = val;
      p_bf[o + ni*16 + fr] = f2bf(val);
    }
  }
}

// ---------------------------------------------------------------------------
// hr = (P @ V) * silu(r) via MFMA. Grid flat: blk*16 + htile (64-wide).
// Custom B staging for the [blk][kc][h][8] vt layout: global chunk c of row h
// lives at blk*131072 + c*8192 + h*8; same glds16 slot/swizzle scheme as the
// GEMM core (slot relation (c + (row&7))&7 preserved on store and read).
// ---------------------------------------------------------------------------
__global__ __launch_bounds__(256, 6) void attn_pv_kernel(
    const bf16_t* __restrict__ p_bf, const bf16_t* __restrict__ vt,
    const bf16_t* __restrict__ base, bf16_t* __restrict__ hr)
{
  __shared__ __align__(16) char smem[24576];
  bf16_t* As = (bf16_t*)smem;
  bf16_t* Bs = (bf16_t*)(smem + 16384);
  bf16_t* Cs = (bf16_t*)smem;
  int blk = blockIdx.x >> 4, ht = blockIdx.x & 15;
  int b = blk >> 4, n = blk & 15;
  const int K = 128;
  int tid = threadIdx.x;
  int wave = tid >> 6, lane = tid & 63;
  int lrow = lane >> 3, lchunk = ((lane & 7) - lrow) & 7;
  const bf16_t* Ag = p_bf + (size_t)blk*16384
                     + (size_t)(wave*32 + lrow)*K + lchunk*8;
  const bf16_t* Bg = vt + (size_t)blk*131072 + (size_t)lchunk*8192
                     + (size_t)(ht*64 + wave*16 + lrow)*8;
  int wm = wave >> 1, wn = wave & 1;
  int fr = lane & 15, fq = lane >> 4;
  f32x4 acc[4][2];
  #pragma unroll
  for (int i = 0; i < 4; ++i)
    #pragma unroll
    for (int j = 0; j < 2; ++j)
      acc[i][j] = (f32x4){0.f,0.f,0.f,0.f};
  for (int k0 = 0; k0 < K; k0 += 64) {
    __syncthreads();
    #pragma unroll
    for (int j = 0; j < 4; ++j)
      glds16(Ag + (size_t)j*8*K + k0, As + (wave*32 + j*8)*64);
    #pragma unroll
    for (int j = 0; j < 2; ++j)
      glds16(Bg + (size_t)(k0 >> 3)*8192 + j*64, Bs + (wave*16 + j*8)*64);
    __syncthreads();
    #pragma unroll
    for (int kk = 0; kk < 2; ++kk) {
      short8 af[4], bfr[2];
      #pragma unroll
      for (int mi = 0; mi < 4; ++mi) {
        int R = wm*64 + mi*16 + fr;
        af[mi] = *(const short8*)&As[R*64 + (((kk<<2)+fq+R)&7)*8];
      }
      #pragma unroll
      for (int ni = 0; ni < 2; ++ni) {
        int R = wn*32 + ni*16 + fr;
        bfr[ni] = *(const short8*)&Bs[R*64 + (((kk<<2)+fq+R)&7)*8];
      }
      #pragma unroll
      for (int mi = 0; mi < 4; ++mi)
        #pragma unroll
        for (int ni = 0; ni < 2; ++ni)
          acc[mi][ni] = __builtin_amdgcn_mfma_f32_16x16x32_bf16(
              af[mi], bfr[ni], acc[mi][ni], 0, 0, 0);
    }
  }
  __syncthreads();
  #pragma unroll
  for (int ni = 0; ni < 2; ++ni) {
    int cl = wn*32 + ni*16 + fr;
    int hg = ht*64 + cl;
    #pragma unroll
    for (int mi = 0; mi < 4; ++mi) {
      #pragma unroll
      for (int r = 0; r < 4; ++r) {
        int ml = wm*64 + mi*16 + fq*4 + r;
        size_t rowg = (size_t)((n*128 + ml)*B_DIM + b);
        float rg = bf2f(base[rowg*BASE_N + 640 + hg]);
        Cs[ml*72 + cl] = f2bf(acc[mi][ni][r]*siluf_(rg));
      }
    }
  }
  __syncthreads();
  int row = tid >> 1, c0 = (tid & 1)*32;
  size_t rowg = (size_t)((n*128 + row)*B_DIM + b);
  #pragma unroll
  for (int q = 0; q < 4; ++q)
    *(uint4*)(hr + rowg*H_DIM + ht*64 + c0 + q*8) =
        *(const uint4*)&Cs[row*72 + c0 + q*8];
}

// ---------------------------------------------------------------------------
// out = residual + u*(h2 - residual), then RMSNorm * norm_scalar.
// 256 threads = 4 rows per block (one wave per row).
// ---------------------------------------------------------------------------
__global__ __launch_bounds__(256) void final_kernel(
    const float* __restrict__ x, const bf16_t* __restrict__ h2,
    const bf16_t* __restrict__ base, const float* __restrict__ ns,
    float* __restrict__ out)
{
  int row = blockIdx.x*4 + (threadIdx.x >> 6);
  int t = threadIdx.x & 63;
  size_t ro = (size_t)row*D_DIM + t*8;
  float xv[8]; load8(x + ro, xv);
  float hv[8]; load8(h2 + ro, hv);
  float uv[8]; load8(base + (size_t)row*BASE_N + t*8, uv);
  float o[8];
  float ss = 0.f;
  #pragma unroll
  for (int i = 0; i < 8; ++i) {
    float u = sigmoidf_(uv[i]);
    o[i] = xv[i] + u*(hv[i] - xv[i]);
    ss += o[i]*o[i];
  }
  #pragma unroll
  for (int m = 1; m < 64; m <<= 1) ss += __shfl_xor(ss, m);
  float inv = rsqrtf(ss*(1.f/(float)D_DIM) + 1e-6f) * ns[0];
  float4 r0, r1;
  r0.x = o[0]*inv; r0.y = o[1]*inv; r0.z = o[2]*inv; r0.w = o[3]*inv;
  r1.x = o[4]*inv; r1.y = o[5]*inv; r1.z = o[6]*inv; r1.w = o[7]*inv;
  *(float4*)(out + ro) = r0;
  *(float4*)(out + ro + 4) = r1;
}

// ---------------------------------------------------------------------------
extern "C" void kernel_launch(void* const* d_in, const int* in_sizes, int n_in,
                              void* d_out, int out_size, void* d_ws, size_t ws_size,
                              hipStream_t stream)
{
  const float* x     = (const float*)d_in[0];
  const float* delta = (const float*)d_in[1];
  const float* alpha = (const float*)d_in[2];
  const float* beta  = (const float*)d_in[3];
  const float* gamma = (const float*)d_in[4];
  const float* omega = (const float*)d_in[5];
  const float* Wv    = (const float*)d_in[6];
  const float* bv    = (const float*)d_in[7];
  const float* Wmx   = (const float*)d_in[8];
  const float* bmx   = (const float*)d_in[9];
  const float* Wh    = (const float*)d_in[10];
  const float* bh    = (const float*)d_in[11];
  const float* qkg   = (const float*)d_in[12];
  const float* qkb   = (const float*)d_in[13];
  const float* rpb   = (const float*)d_in[14];
  const float* ns    = (const float*)d_in[15];

  float* out  = (float*)d_out;
  float* attn = out + (size_t)ROWS*D_DIM;

  char* outb = (char*)d_out;
  bf16_t* x_bf  = (bf16_t*)outb;            // dead after Wv GEMM
  bf16_t* p_bf  = (bf16_t*)outb;            // written by scores, read by PV
  bf16_t* Wv_t  = (bf16_t*)(outb + 33554432ull);
  bf16_t* Wmx_t = (bf16_t*)(outb + 34603008ull);
  bf16_t* Wh_t  = (bf16_t*)(outb + 36831232ull);

  const size_t WS_NEED = 310378496ull;
  if (ws_size < WS_NEED) return;
  char* wsb = (char*)d_ws;
  bf16_t* mx_bf   = (bf16_t*)(wsb);
  bf16_t* vt      = (bf16_t*)(wsb + 33554432ull);
  bf16_t* base_bf = (bf16_t*)(wsb + 100663296ull);
  bf16_t* hr_bf   = (bf16_t*)(wsb + 243269632ull);
  float*  carry   = (float*)(wsb + 100663296ull);
  bf16_t* h2_bf   = mx_bf;

  // EMA carry + all three weight transposes in one launch
  pre_kernel<<<3136, 256, 0, stream>>>(x, delta, alpha, x_bf, carry,
                                       Wv, Wmx, Wh, Wv_t, Wmx_t, Wh_t);
  ema_combine_kernel<<<32, 256, 0, stream>>>(delta, alpha, carry);
  ema_apply_kernel<<<1024, 256, 0, stream>>>(x_bf, delta, alpha, beta, gamma,
                                             omega, carry, mx_bf);
  // merged: base = mx @ Wmx + bmx  AND  vt = silu(x @ Wv + bv)
  gemm_wmx_v_kernel<<<12800, 256, 0, stream>>>(
      mx_bf, Wmx_t, bmx, base_bf, x_bf, Wv_t, bv, vt);
  // attn probs (fp32 -> d_out, bf16 -> p_bf); 2 q-half blocks per (b,n)
  attn_scores_mfma_kernel<<<B_DIM*NC*2, 256, 0, stream>>>(
      base_bf, qkg, qkb, rpb, attn, p_bf);
  // hr = (P @ V) * silu(r)  (16 h-tiles of 64)
  attn_pv_kernel<<<4096, 256, 0, stream>>>(p_bf, vt, base_bf, hr_bf);
  // h2 = silu(hx + hr @ Wh + bh) (N=512 -> 8 tiles of 64)
  mfma_gemm_kernel<<<2048, 256, 0, stream>>>(
      hr_bf, Wh_t, bh, base_bf + 1664, BASE_N, h2_bf, D_DIM, H_DIM, 8, 1);
  // gated residual + RMSNorm
  final_kernel<<<ROWS/4, 256, 0, stream>>>(x, h2_bf, base_bf, ns, out);
}